// Round 7
// baseline (303.327 us; speedup 1.0000x reference)
//
#include <hip/hip_runtime.h>
#include <hip/hip_fp16.h>
#include <math.h>

#define N_NODES 100000
#define N_RELS  500
#define DIM     64
#define N_EDGES 1000000
#define SLOPE   0.01f
#define RSUB    4       // blocks per relation in pooling
#define SC_EDGES 2048   // edges per block in hist/scatter partition
#define NB_E    489     // ceil(N_EDGES / SC_EDGES)
#define NBKT    196     // src buckets (src >> 9, 512 nodes each)
#define BSH     9
#define NROWS   (N_RELS + NBKT)   // 696 rows in blkhist/blkbase
#define BMAX    5632    // LDS slots per bucket in k_sortb

// bf16 pack/unpack (round-to-nearest-even)
__device__ __forceinline__ unsigned short f2bf(float f) {
    unsigned int u = __float_as_uint(f);
    u += 0x7FFFu + ((u >> 16) & 1u);
    return (unsigned short)(u >> 16);
}
__device__ __forceinline__ float bfl(unsigned int u) { return __uint_as_float(u << 16); }
__device__ __forceinline__ float bfh(unsigned int u) { return __uint_as_float(u & 0xFFFF0000u); }

// fp8 e5m2 pack/unpack. e5m2 == fp16 with mantissa truncated to 2 bits:
// decode is (byte<<8) reinterpreted as half; encode is f32->f16 RTNE then
// RTNE-round to the upper byte. Used ONLY for the relation-pooling shadow of
// h (mean over ~2000 edges + |W_rel3|<=0.072 attenuate the quant noise).
__device__ __forceinline__ unsigned int f2e5m2(float f) {
    __half h = __float2half_rn(f);
    unsigned short hu;
    __builtin_memcpy(&hu, &h, 2);
    unsigned int u = hu;
    u += 0x7Fu + ((u >> 8) & 1u);
    return (u >> 8) & 0xFFu;
}
__device__ __forceinline__ float e5d(unsigned int b) {
    unsigned short u = (unsigned short)(b << 8);
    __half h;
    __builtin_memcpy(&h, &u, 2);
    return __half2float(h);
}
__device__ __forceinline__ void acc8(float* a, unsigned int x, unsigned int y) {
    a[0] += e5d(x & 255u);         a[1] += e5d((x >> 8) & 255u);
    a[2] += e5d((x >> 16) & 255u); a[3] += e5d(x >> 24);
    a[4] += e5d(y & 255u);         a[5] += e5d((y >> 8) & 255u);
    a[6] += e5d((y >> 16) & 255u); a[7] += e5d(y >> 24);
}
__device__ __forceinline__ void acc16(float* a, uint4 w) {
    acc8(a, w.x, w.y);
    acc8(a + 8, w.z, w.w);
}
// accumulate one attention stream: a[0..7] += b * (V + W) for 8 bf16 dims
__device__ __forceinline__ void accvw(float* a, float b, uint4 vv, uint4 ww) {
    a[0] += b * (bfl(vv.x) + bfl(ww.x));
    a[1] += b * (bfh(vv.x) + bfh(ww.x));
    a[2] += b * (bfl(vv.y) + bfl(ww.y));
    a[3] += b * (bfh(vv.y) + bfh(ww.y));
    a[4] += b * (bfl(vv.z) + bfl(ww.z));
    a[5] += b * (bfh(vv.z) + bfh(ww.z));
    a[6] += b * (bfl(vv.w) + bfl(ww.w));
    a[7] += b * (bfh(vv.w) + bfh(ww.w));
}

// ---------------------------------------------------------------------------
// K0: fold the small matrices.
// ---------------------------------------------------------------------------
__global__ void k_fold(const float* __restrict__ W_ent, const float* __restrict__ b_ent,
                       const float* __restrict__ W_relL, const float* __restrict__ b_relL,
                       const float* __restrict__ W_rel2, const float* __restrict__ b_rel2,
                       const float* __restrict__ W_fc, const float* __restrict__ b_fc,
                       float* __restrict__ Wcat, float* __restrict__ dcat,
                       float* __restrict__ MW, float* __restrict__ MQ,
                       float* __restrict__ dW, float* __restrict__ dQ) {
    int idx = blockIdx.x * 256 + threadIdx.x;
    if (idx < 8192) {
        int k = idx >> 7;
        int j2 = idx & 127;
        int jj = j2 & 63;
        int off = (j2 >> 6) * 64;
        float s = 0.f;
        for (int i = 0; i < 64; i++) s += W_fc[jj*192 + off + i] * W_ent[i*64 + k];
        Wcat[k*128 + j2] = s;
    } else if (idx < 12288) {
        int rem = idx - 8192;
        int j = rem >> 6, i = rem & 63;
        float s = 0.f;
        for (int k = 0; k < 64; k++) s += W_fc[j*192 + 128 + k] * W_relL[k*64 + i];
        MW[j*64 + i] = s;
    } else if (idx < 16384) {
        int rem = idx - 12288;
        int j = rem >> 6, i = rem & 63;
        float s = 0.f;
        for (int k = 0; k < 64; k++) s += W_rel2[j*64 + k] * W_relL[k*64 + i];
        MQ[j*64 + i] = s;
    } else if (idx < 16512) {
        int j2 = idx - 16384;
        int jj = j2 & 63;
        int off = (j2 >> 6) * 64;
        float s = 0.f;
        for (int i = 0; i < 64; i++) s += b_ent[i] * W_fc[jj*192 + off + i];
        dcat[j2] = s;
    } else if (idx < 16640) {
        int rem = idx - 16512;
        int vec = rem >> 6, j = rem & 63;
        if (vec == 0) {
            float s = b_fc[j];
            for (int k = 0; k < 64; k++) s += b_relL[k] * W_fc[j*192 + 128 + k];
            dW[j] = s;
        } else {
            float s = b_rel2[j];
            for (int k = 0; k < 64; k++) s += b_relL[k] * W_rel2[j*64 + k];
            dQ[j] = s;
        }
    }
}

// ---------------------------------------------------------------------------
// K1: per-node projections (LDS-tiled GEMM). U -> fp32 (output buffer);
// V -> bf16 shadow only.
// ---------------------------------------------------------------------------
__global__ __launch_bounds__(256) void k_node(const float* __restrict__ ent,
        const float* __restrict__ Wcat, const float* __restrict__ dcat,
        const float* __restrict__ W_a,
        float* __restrict__ Uout, unsigned short* __restrict__ V16,
        float* __restrict__ us, float* __restrict__ vs) {
    __shared__ float sA[64][68];
    __shared__ float sW[64][128];
    int t = threadIdx.x;
    int tile0 = blockIdx.x * 64;
    for (int i = t; i < 2048; i += 256)
        ((float4*)sW)[i] = ((const float4*)Wcat)[i];
    for (int f = t; f < 1024; f += 256) {
        int n = f >> 4, k4 = f & 15;
        float4 v4 = (tile0 + n < N_NODES)
            ? ((const float4*)(ent + (size_t)(tile0 + n) * 64))[k4]
            : make_float4(0.f, 0.f, 0.f, 0.f);
        *(float4*)&sA[n][k4 * 4] = v4;
    }
    __syncthreads();

    int ng = t >> 4;
    int jg = t & 15;
    int n0 = ng * 4;
    int j0 = jg * 8;

    float4 d0 = *(const float4*)(dcat + j0);
    float4 d1 = *(const float4*)(dcat + j0 + 4);
    float acc[4][8];
    #pragma unroll
    for (int a = 0; a < 4; a++) {
        acc[a][0] = d0.x; acc[a][1] = d0.y; acc[a][2] = d0.z; acc[a][3] = d0.w;
        acc[a][4] = d1.x; acc[a][5] = d1.y; acc[a][6] = d1.z; acc[a][7] = d1.w;
    }

    #pragma unroll 4
    for (int k = 0; k < 64; k++) {
        float4 w0 = *(const float4*)&sW[k][j0];
        float4 w1 = *(const float4*)&sW[k][j0 + 4];
        float e0 = sA[n0][k], e1 = sA[n0+1][k], e2 = sA[n0+2][k], e3 = sA[n0+3][k];
        float e[4] = {e0, e1, e2, e3};
        #pragma unroll
        for (int a = 0; a < 4; a++) {
            acc[a][0] += e[a] * w0.x; acc[a][1] += e[a] * w0.y;
            acc[a][2] += e[a] * w0.z; acc[a][3] += e[a] * w0.w;
            acc[a][4] += e[a] * w1.x; acc[a][5] += e[a] * w1.y;
            acc[a][6] += e[a] * w1.z; acc[a][7] += e[a] * w1.w;
        }
    }

    int jw = j0 & 63;
    float4 wa0 = *(const float4*)(W_a + jw);
    float4 wa1 = *(const float4*)(W_a + jw + 4);
    float part[4];
    #pragma unroll
    for (int a = 0; a < 4; a++) {
        part[a] = acc[a][0]*wa0.x + acc[a][1]*wa0.y + acc[a][2]*wa0.z + acc[a][3]*wa0.w
                + acc[a][4]*wa1.x + acc[a][5]*wa1.y + acc[a][6]*wa1.z + acc[a][7]*wa1.w;
    }
    #pragma unroll
    for (int m = 1; m <= 4; m <<= 1) {
        #pragma unroll
        for (int a = 0; a < 4; a++) part[a] += __shfl_xor(part[a], m, 64);
    }
    if ((jg & 7) == 0) {
        float* sv = (jg < 8) ? us : vs;
        #pragma unroll
        for (int a = 0; a < 4; a++)
            if (tile0 + n0 + a < N_NODES) sv[tile0 + n0 + a] = part[a];
    }

    #pragma unroll
    for (int a = 0; a < 4; a++) {
        int n = tile0 + n0 + a;
        if (n >= N_NODES) break;
        if (jg < 8) {
            float4 o0 = make_float4(acc[a][0], acc[a][1], acc[a][2], acc[a][3]);
            float4 o1 = make_float4(acc[a][4], acc[a][5], acc[a][6], acc[a][7]);
            float* base = Uout + (size_t)n * 64 + j0;
            *(float4*)(base) = o0;
            *(float4*)(base + 4) = o1;
        } else {
            uint4 pv;
            pv.x = (unsigned int)f2bf(acc[a][0]) | ((unsigned int)f2bf(acc[a][1]) << 16);
            pv.y = (unsigned int)f2bf(acc[a][2]) | ((unsigned int)f2bf(acc[a][3]) << 16);
            pv.z = (unsigned int)f2bf(acc[a][4]) | ((unsigned int)f2bf(acc[a][5]) << 16);
            pv.w = (unsigned int)f2bf(acc[a][6]) | ((unsigned int)f2bf(acc[a][7]) << 16);
            *(uint4*)(V16 + (size_t)n * 64 + (j0 - 64)) = pv;
        }
    }
}

// K2: per-relation projections. Wr -> bf16 shadow; Qr fp32; wsr fp32.
__global__ __launch_bounds__(256, 2) void k_relproj(const float* __restrict__ relE,
        const float* __restrict__ MW, const float* __restrict__ MQ,
        const float* __restrict__ dW, const float* __restrict__ dQ,
        const float* __restrict__ W_a,
        unsigned short* __restrict__ Wr16, float* __restrict__ Qr, float* __restrict__ wsr) {
    int lane = threadIdx.x & 63;
    int wv = threadIdx.x >> 6;
    float mw[64], mq[64];
    #pragma unroll
    for (int i = 0; i < 64; i++) { mw[i] = MW[lane*64 + i]; mq[i] = MQ[lane*64 + i]; }
    float dw = dW[lane], dq = dQ[lane], wa = W_a[lane];
    int r = blockIdx.x * 4 + wv;
    if (r >= N_RELS) return;
    float e = relE[(size_t)r * 64 + lane];
    float w = dw, q = dq;
    #pragma unroll
    for (int i = 0; i < 64; i++) {
        float ei = __shfl(e, i, 64);
        w += ei * mw[i];
        q += ei * mq[i];
    }
    Wr16[(size_t)r * 64 + lane] = f2bf(w);
    Qr[(size_t)r * 64 + lane] = q;
    float tw = w * wa;
    #pragma unroll
    for (int o = 32; o; o >>= 1) tw += __shfl_xor(tw, o, 64);
    if (lane == 0) wsr[r] = tw;
}

__global__ void k_zero(int* __restrict__ a, int n) {
    int g = blockIdx.x * 256 + threadIdx.x;
    if (g < n) a[g] = 0;
}

// ---------------------------------------------------------------------------
// K3: histogram (LDS hists: 500 rels + 196 src-buckets; transposed blkhist).
// ---------------------------------------------------------------------------
__global__ __launch_bounds__(256) void k_hist(const int* __restrict__ src, const int* __restrict__ rel,
        int* __restrict__ cnt_rel, int* __restrict__ bucket_cnt, int* __restrict__ blkhist) {
    __shared__ int lcntR[N_RELS];
    __shared__ int lcntS[NBKT];
    int t = threadIdx.x;
    for (int r = t; r < N_RELS; r += 256) lcntR[r] = 0;
    for (int b = t; b < NBKT; b += 256) lcntS[b] = 0;
    __syncthreads();
    int base = blockIdx.x * SC_EDGES;
    if (base + SC_EDGES <= N_EDGES) {
        int e0 = base + t * 8;
        int4 sa = *(const int4*)(src + e0);
        int4 sb = *(const int4*)(src + e0 + 4);
        int4 ra = *(const int4*)(rel + e0);
        int4 rb = *(const int4*)(rel + e0 + 4);
        atomicAdd(&lcntS[sa.x >> BSH], 1); atomicAdd(&lcntS[sa.y >> BSH], 1);
        atomicAdd(&lcntS[sa.z >> BSH], 1); atomicAdd(&lcntS[sa.w >> BSH], 1);
        atomicAdd(&lcntS[sb.x >> BSH], 1); atomicAdd(&lcntS[sb.y >> BSH], 1);
        atomicAdd(&lcntS[sb.z >> BSH], 1); atomicAdd(&lcntS[sb.w >> BSH], 1);
        atomicAdd(&lcntR[ra.x], 1); atomicAdd(&lcntR[ra.y], 1);
        atomicAdd(&lcntR[ra.z], 1); atomicAdd(&lcntR[ra.w], 1);
        atomicAdd(&lcntR[rb.x], 1); atomicAdd(&lcntR[rb.y], 1);
        atomicAdd(&lcntR[rb.z], 1); atomicAdd(&lcntR[rb.w], 1);
    } else {
        for (int g = base + t; g < N_EDGES; g += 256) {
            atomicAdd(&lcntS[src[g] >> BSH], 1);
            atomicAdd(&lcntR[rel[g]], 1);
        }
    }
    __syncthreads();
    for (int r = t; r < N_RELS; r += 256) {
        int c = lcntR[r];
        blkhist[(size_t)r * NB_E + blockIdx.x] = c;
        if (c) atomicAdd(&cnt_rel[r], c);
    }
    for (int b = t; b < NBKT; b += 256) {
        int c = lcntS[b];
        blkhist[(size_t)(N_RELS + b) * NB_E + blockIdx.x] = c;
        if (c) atomicAdd(&bucket_cnt[b], c);
    }
}

// K4a: two small exclusive scans (rels, buckets).
__global__ void k_scan_two(const int* __restrict__ cnt_rel, const int* __restrict__ bucket_cnt,
                           int* __restrict__ starts) {
    __shared__ int tot[256];
    int t = threadIdx.x;
    const int* cnt = blockIdx.x ? bucket_cnt : cnt_rel;
    int n = blockIdx.x ? NBKT : N_RELS;
    int* out = starts + (blockIdx.x ? N_RELS : 0);
    int myv[4];
    int mySum = 0;
    for (int q = 0; q < 4; q++) {
        int g = t * 4 + q;
        int v = (g < n) ? cnt[g] : 0;
        myv[q] = v; mySum += v;
    }
    tot[t] = mySum;
    __syncthreads();
    for (int o = 1; o < 256; o <<= 1) {
        int u = (t >= o) ? tot[t - o] : 0;
        __syncthreads();
        tot[t] += u;
        __syncthreads();
    }
    int run = tot[t] - mySum;
    for (int q = 0; q < 4; q++) {
        int g = t * 4 + q;
        if (g < n) out[g] = run;
        run += myv[q];
    }
}

// K4b: per-(row, block) bases; one wave per row.
__global__ __launch_bounds__(256) void k_scan_relblk(const int* __restrict__ starts,
        const int* __restrict__ blkhist, int* __restrict__ blkbase) {
    int lane = threadIdx.x & 63;
    int row = (blockIdx.x * 256 + threadIdx.x) >> 6;
    if (row >= NROWS) return;
    int run = starts[row];
    for (int base = 0; base < NB_E; base += 64) {
        int b = base + lane;
        int v = (b < NB_E) ? blkhist[(size_t)row * NB_E + b] : 0;
        int x = v;
        #pragma unroll
        for (int o = 1; o < 64; o <<= 1) {
            int y = __shfl_up(x, o, 64);
            if (lane >= o) x += y;
        }
        if (b < NB_E) blkbase[(size_t)row * NB_E + b] = run + (x - v);
        run += __shfl(x, 63, 64);
    }
}

// ---------------------------------------------------------------------------
// K5: pass-A scatter (no global atomics).
// ---------------------------------------------------------------------------
__global__ __launch_bounds__(256) void k_scatter(const int* __restrict__ src, const int* __restrict__ dst,
        const int* __restrict__ rel, const int* __restrict__ blkbase,
        int2* __restrict__ pay_rel, int* __restrict__ stg_a, int* __restrict__ stg_b) {
    __shared__ int lbaseR[N_RELS];
    __shared__ int loffR[N_RELS];
    __shared__ int lbaseS[NBKT];
    __shared__ int loffS[NBKT];
    int t = threadIdx.x;
    for (int r = t; r < N_RELS; r += 256) {
        lbaseR[r] = blkbase[(size_t)r * NB_E + blockIdx.x];
        loffR[r] = 0;
    }
    for (int b = t; b < NBKT; b += 256) {
        lbaseS[b] = blkbase[(size_t)(N_RELS + b) * NB_E + blockIdx.x];
        loffS[b] = 0;
    }
    __syncthreads();
    int base = blockIdx.x * SC_EDGES;
    if (base + SC_EDGES <= N_EDGES) {
        int e0 = base + t * 8;
        int4 sa = *(const int4*)(src + e0);
        int4 sb = *(const int4*)(src + e0 + 4);
        int4 da = *(const int4*)(dst + e0);
        int4 db = *(const int4*)(dst + e0 + 4);
        int4 ra = *(const int4*)(rel + e0);
        int4 rb = *(const int4*)(rel + e0 + 4);
        int s[8] = {sa.x, sa.y, sa.z, sa.w, sb.x, sb.y, sb.z, sb.w};
        int d[8] = {da.x, da.y, da.z, da.w, db.x, db.y, db.z, db.w};
        int r8[8] = {ra.x, ra.y, ra.z, ra.w, rb.x, rb.y, rb.z, rb.w};
        int p[8], q[8];
        #pragma unroll
        for (int j = 0; j < 8; j++) q[j] = lbaseR[r8[j]] + atomicAdd(&loffR[r8[j]], 1);
        #pragma unroll
        for (int j = 0; j < 8; j++) p[j] = lbaseS[s[j] >> BSH] + atomicAdd(&loffS[s[j] >> BSH], 1);
        #pragma unroll
        for (int j = 0; j < 8; j++) pay_rel[q[j]] = make_int2(s[j], d[j]);
        #pragma unroll
        for (int j = 0; j < 8; j++) stg_a[p[j]] = d[j];
        #pragma unroll
        for (int j = 0; j < 8; j++) stg_b[p[j]] = ((s[j] & 511) << 9) | r8[j];
    } else {
        for (int g = base + t; g < N_EDGES; g += 256) {
            int s = src[g], d = dst[g], r = rel[g];
            int q = lbaseR[r] + atomicAdd(&loffR[r], 1);
            pay_rel[q] = make_int2(s, d);
            int sb2 = s >> BSH;
            int p = lbaseS[sb2] + atomicAdd(&loffS[sb2], 1);
            stg_a[p] = d;
            stg_b[p] = ((s & 511) << 9) | r;
        }
    }
}

// ---------------------------------------------------------------------------
// K5b: pass-B bucket counting sort -> pay_src + start/cnt_src. Also computes
// per-edge attention weight b = exp(leaky(us+vs+wsr+ba)) -> pay_b (coalesced)
// and per-node bsum (LDS float atomics) -> bsum_arr.
// ---------------------------------------------------------------------------
__global__ __launch_bounds__(256) void k_sortb(const int* __restrict__ stg_a,
        const int* __restrict__ stg_b, const int* __restrict__ starts,
        const int* __restrict__ bucket_cnt,
        const float* __restrict__ us, const float* __restrict__ vs,
        const float* __restrict__ wsr, const float* __restrict__ b_a_p,
        int2* __restrict__ pay_src, float* __restrict__ pay_b,
        int* __restrict__ start_src, int* __restrict__ cnt_src,
        float* __restrict__ bsum_arr) {
    __shared__ int hist[512];
    __shared__ int lstart[512];
    __shared__ int loff[512];
    __shared__ int tot[256];
    __shared__ float lbsum[512];
    __shared__ int2 lpay[BMAX];
    int bkt = blockIdx.x;
    int base = starts[N_RELS + bkt];
    int n = bucket_cnt[bkt];
    int t = threadIdx.x;
    float ba = b_a_p[0];
    hist[t] = 0; hist[t + 256] = 0;
    lbsum[t] = 0.f; lbsum[t + 256] = 0.f;
    __syncthreads();
    for (int i = t; i < n; i += 256)
        atomicAdd(&hist[stg_b[base + i] >> 9], 1);
    __syncthreads();
    int v0 = hist[t * 2], v1 = hist[t * 2 + 1];
    int mySum = v0 + v1;
    tot[t] = mySum;
    __syncthreads();
    for (int o = 1; o < 256; o <<= 1) {
        int u = (t >= o) ? tot[t - o] : 0;
        __syncthreads();
        tot[t] += u;
        __syncthreads();
    }
    int run = tot[t] - mySum;
    lstart[t * 2] = run;
    lstart[t * 2 + 1] = run + v0;
    loff[t * 2] = 0;
    loff[t * 2 + 1] = 0;
    int node0 = bkt * 512 + t * 2;
    if (node0 < N_NODES) { start_src[node0] = base + run; cnt_src[node0] = v0; }
    if (node0 + 1 < N_NODES) { start_src[node0 + 1] = base + run + v0; cnt_src[node0 + 1] = v1; }
    __syncthreads();
    bool fits = (n <= BMAX);
    for (int i = t; i < n; i += 256) {
        int bb = stg_b[base + i];
        int d = stg_a[base + i];
        int lo = bb >> 9;
        int pos = lstart[lo] + atomicAdd(&loff[lo], 1);
        if (fits) {
            lpay[pos] = make_int2(d, bb);
        } else {
            int r = bb & 511;
            int s = bkt * 512 + lo;
            float t0 = us[s] + vs[d] + wsr[r] + ba;
            t0 = t0 > 0.f ? t0 : SLOPE * t0;
            float b = expf(t0);
            pay_src[base + pos] = make_int2(d, r);
            pay_b[base + pos] = b;
            atomicAdd(&lbsum[lo], b);
        }
    }
    __syncthreads();
    if (fits) {
        for (int i = t; i < n; i += 256) {
            int2 pr = lpay[i];
            int bb = pr.y;
            int lo = bb >> 9;
            int r = bb & 511;
            int s = bkt * 512 + lo;
            float t0 = us[s] + vs[pr.x] + wsr[r] + ba;
            t0 = t0 > 0.f ? t0 : SLOPE * t0;
            float b = expf(t0);
            pay_src[base + i] = make_int2(pr.x, r);
            pay_b[base + i] = b;
            atomicAdd(&lbsum[lo], b);
        }
        __syncthreads();
    }
    if (node0 < N_NODES) bsum_arr[node0] = lbsum[t * 2];
    if (node0 + 1 < N_NODES) bsum_arr[node0 + 1] = lbsum[t * 2 + 1];
}

// ---------------------------------------------------------------------------
// K6: aggregation. 4 nodes per wave (16 lanes each, 8 lanes per edge row);
// b/bsum precomputed; payload broadcast via same-address loads; dual-edge
// streams (4 gather rows in flight per lane) + CROSS-ITERATION pay prefetch:
// next iteration's pay/pay_b are loaded while the current gathers are in
// flight, removing the serial pay-load -> gather chain each iteration.
// h shadow emitted as fp8 e5m2.
// ---------------------------------------------------------------------------
__global__ __launch_bounds__(256) void k_attn(const int2* __restrict__ pay,
        const float* __restrict__ pay_b,
        const int* __restrict__ start_src, const int* __restrict__ cnt_src,
        const float* __restrict__ bsum_arr,
        const unsigned short* __restrict__ V16, const unsigned short* __restrict__ Wr16,
        float* __restrict__ h, unsigned char* __restrict__ h8) {
    int lane = threadIdx.x & 63;
    int wv = threadIdx.x >> 6;
    int quarter = lane >> 4;
    int lq = lane & 15;
    int slot = lq >> 3;      // 0/1: even/odd edge stream
    int li = lq & 7;         // dim octet
    int n = blockIdx.x * 16 + wv * 4 + quarter;
    if (n >= N_NODES) return;
    int st = start_src[n];
    int cnt = cnt_src[n];
    if (cnt == 0) {
        if (lq < 8) {
            float* hp = h + (size_t)n * 64 + lq * 8;
            *(float4*)hp = make_float4(0.f, 0.f, 0.f, 0.f);
            *(float4*)(hp + 4) = make_float4(0.f, 0.f, 0.f, 0.f);
            *(uint2*)(h8 + (size_t)n * 64 + lq * 8) = make_uint2(0u, 0u);
        }
        return;
    }
    float inv = 1.f / bsum_arr[n];
    float a[8] = {0.f, 0.f, 0.f, 0.f, 0.f, 0.f, 0.f, 0.f};
    // two streams at e, e+2; step 4; branchless masking (b=0, index clamp to 0)
    int eA = slot;
    int eB = slot + 2;
    bool vA = eA < cnt;
    bool vB = eB < cnt;
    int cA = vA ? eA : 0;
    int cB = vB ? eB : 0;
    float bA = vA ? pay_b[st + cA] : 0.f;
    float bB = vB ? pay_b[st + cB] : 0.f;
    int2 pA = pay[st + cA];
    int2 pB = pay[st + cB];
    while (vA) {
        // issue all 4 gathers first (2 edges x V16+Wr16)
        uint4 vvA = *(const uint4*)(V16 + (size_t)pA.x * 64 + li * 8);
        uint4 wwA = *(const uint4*)(Wr16 + (size_t)pA.y * 64 + li * 8);
        uint4 vvB = *(const uint4*)(V16 + (size_t)pB.x * 64 + li * 8);
        uint4 wwB = *(const uint4*)(Wr16 + (size_t)pB.y * 64 + li * 8);
        // prefetch next iteration's pay/pay_b while gathers are in flight
        int nA = eA + 4, nB = eB + 4;
        bool wA = nA < cnt, wB = nB < cnt;
        int dA = wA ? nA : 0, dB = wB ? nB : 0;
        float nbA = wA ? pay_b[st + dA] : 0.f;
        float nbB = wB ? pay_b[st + dB] : 0.f;
        int2 npA = pay[st + dA];
        int2 npB = pay[st + dB];
        // consume
        accvw(a, bA, vvA, wwA);
        accvw(a, bB, vvB, wwB);
        eA = nA; eB = nB; vA = wA; vB = wB;
        bA = nbA; bB = nbB; pA = npA; pB = npB;
    }
    #pragma unroll
    for (int d = 0; d < 8; d++) a[d] += __shfl_xor(a[d], 8, 64);
    if (slot == 0) {
        float* hp = h + (size_t)n * 64 + li * 8;
        float o[8];
        #pragma unroll
        for (int d = 0; d < 8; d++) o[d] = hp[d] + a[d] * inv;
        *(float4*)hp = make_float4(o[0], o[1], o[2], o[3]);
        *(float4*)(hp + 4) = make_float4(o[4], o[5], o[6], o[7]);
        uint2 p8;
        p8.x = f2e5m2(o[0]) | (f2e5m2(o[1]) << 8) | (f2e5m2(o[2]) << 16) | (f2e5m2(o[3]) << 24);
        p8.y = f2e5m2(o[4]) | (f2e5m2(o[5]) << 8) | (f2e5m2(o[6]) << 16) | (f2e5m2(o[7]) << 24);
        *(uint2*)(h8 + (size_t)n * 64 + li * 8) = p8;
    }
}

// ---------------------------------------------------------------------------
// K7: relation pooling over fp8 h8. 4 lanes per 64 B row (uint4 = 16 B/lane),
// 6 gather streams, cross-iteration pay prefetch, shuffle-based reduce.
// Each block writes its 128-float partial to part[block] (no atomics, no
// zero-init needed); k_relfin sums the RSUB partials.
// Lane map: li = t&3 (row quarter), side = (t>>2)&1 (src/dst), j = t>>3.
// ---------------------------------------------------------------------------
#define RP_STREAMS 6
__global__ __launch_bounds__(256) void k_relpool(const int2* __restrict__ pay,
        const int* __restrict__ start_rel, const int* __restrict__ cnt_rel,
        const unsigned char* __restrict__ h8, float* __restrict__ part) {
    int r = blockIdx.x / RSUB;
    int sub = blockIdx.x % RSUB;
    int st = start_rel[r];
    int cnt = cnt_rel[r];
    int t = threadIdx.x;
    int li = t & 3;           // 16 B quarter of the 64 B row
    int side = (t >> 2) & 1;  // 0=src, 1=dst
    int j = t >> 3;           // 0..31 edge slot within block

    int chunk = (cnt + RSUB - 1) / RSUB;
    int k0 = sub * chunk;
    int k1 = min(k0 + chunk, cnt);
    int len = k1 - k0;

    float a[16];
    #pragma unroll
    for (int d = 0; d < 16; d++) a[d] = 0.f;

    if (len > 0) {
        const int2* pp = pay + st + k0;
        int m[RP_STREAMS]; bool v[RP_STREAMS]; int2 p[RP_STREAMS];
        #pragma unroll
        for (int s = 0; s < RP_STREAMS; s++) {
            m[s] = j + s * 32;
            v[s] = m[s] < len;
            p[s] = v[s] ? pp[m[s]] : make_int2(0, 0);
        }
        for (int base = 0; base < len; base += 32 * RP_STREAMS) {
            // issue all gathers (16 scattered 64 B rows per VMEM instr)
            uint4 hv[RP_STREAMS];
            #pragma unroll
            for (int s = 0; s < RP_STREAMS; s++) {
                int idx = side ? p[s].y : p[s].x;
                hv[s] = *(const uint4*)(h8 + (size_t)idx * 64 + li * 16);
            }
            // prefetch next iteration's pay while gathers are in flight
            int mn[RP_STREAMS]; bool vn[RP_STREAMS]; int2 pn[RP_STREAMS];
            #pragma unroll
            for (int s = 0; s < RP_STREAMS; s++) {
                mn[s] = m[s] + 32 * RP_STREAMS;
                vn[s] = mn[s] < len;
                pn[s] = vn[s] ? pp[mn[s]] : make_int2(0, 0);
            }
            #pragma unroll
            for (int s = 0; s < RP_STREAMS; s++) if (v[s]) acc16(a, hv[s]);
            #pragma unroll
            for (int s = 0; s < RP_STREAMS; s++) { m[s] = mn[s]; v[s] = vn[s]; p[s] = pn[s]; }
        }
    }

    // wave reduce over the 8 j-slots in this wave (lane bits 3,4,5)
    #pragma unroll
    for (int d = 0; d < 16; d++) {
        a[d] += __shfl_xor(a[d], 8, 64);
        a[d] += __shfl_xor(a[d], 16, 64);
        a[d] += __shfl_xor(a[d], 32, 64);
    }

    // cross-wave reduce via tiny LDS (2 KB), then plain partial store
    __shared__ float red[4][8][16];
    int wv = t >> 6;
    int lane = t & 63;
    if (lane < 8) {
        #pragma unroll
        for (int d = 0; d < 16; d++) red[wv][lane][d] = a[d];
    }
    __syncthreads();
    if (t < 128) {
        int sl = t >> 4;   // (side<<2)|li
        int d = t & 15;
        float s = red[0][sl][d] + red[1][sl][d] + red[2][sl][d] + red[3][sl][d];
        int sd = sl >> 2;
        int li2 = sl & 3;
        part[(size_t)blockIdx.x * 128 + sd * 64 + li2 * 16 + d] = s;
    }
}

// K8: sum RSUB partials, mean + h_rel = mean @ W_rel3.T + b_rel3
__global__ void k_relfin(const float* __restrict__ part, const int* __restrict__ cnt_rel,
                         const float* __restrict__ Qr, const float* __restrict__ W_rel3,
                         const float* __restrict__ b_rel3, float* __restrict__ out) {
    int g = blockIdx.x * 256 + threadIdx.x;
    if (g >= N_RELS * 64) return;
    int r = g >> 6;
    int j = g & 63;
    int cnt = cnt_rel[r];
    float invc = 1.f / (float)(cnt > 0 ? cnt : 1);
    const float* p0 = part + (size_t)(r * RSUB) * 128;
    float s = b_rel3[j];
    for (int k = 0; k < 128; k++) {
        float acc = p0[k] + p0[128 + k] + p0[256 + k] + p0[384 + k];
        s += acc * invc * W_rel3[j * 192 + k];
    }
    if (cnt > 0)
        for (int k = 0; k < 64; k++) s += Qr[r * 64 + k] * W_rel3[j * 192 + 128 + k];
    out[g] = s;
}

extern "C" void kernel_launch(void* const* d_in, const int* in_sizes, int n_in,
                              void* d_out, int out_size, void* d_ws, size_t ws_size,
                              hipStream_t stream) {
    const float* ent    = (const float*)d_in[0];
    const float* relE   = (const float*)d_in[1];
    const float* W_ent  = (const float*)d_in[2];
    const float* b_ent  = (const float*)d_in[3];
    const float* W_relL = (const float*)d_in[4];
    const float* b_relL = (const float*)d_in[5];
    const float* W_rel2 = (const float*)d_in[6];
    const float* b_rel2 = (const float*)d_in[7];
    const float* W_rel3 = (const float*)d_in[8];
    const float* b_rel3 = (const float*)d_in[9];
    const float* W_a    = (const float*)d_in[10];
    const float* b_a    = (const float*)d_in[11];
    const float* W_fc   = (const float*)d_in[12];
    const float* b_fc   = (const float*)d_in[13];
    const int* src = (const int*)d_in[14];
    const int* dst = (const int*)d_in[15];
    const int* rel = (const int*)d_in[16];
    float* out = (float*)d_out;

    char* ws = (char*)d_ws;
    size_t off = 0;
    auto alloc = [&](size_t bytes) -> void* {
        void* p = ws + off;
        off += (bytes + 255) & ~(size_t)255;
        return p;
    };
    float* Wcat = (float*)alloc(8192 * 4);
    float* dcat = (float*)alloc(128 * 4);
    float* MW  = (float*)alloc(4096 * 4);
    float* MQ  = (float*)alloc(4096 * 4);
    float* dW  = (float*)alloc(64 * 4);
    float* dQ  = (float*)alloc(64 * 4);
    unsigned short* V16 = (unsigned short*)alloc((size_t)N_NODES * 64 * 2);
    unsigned char* h8 = (unsigned char*)alloc((size_t)N_NODES * 64);
    float* us  = (float*)alloc((size_t)N_NODES * 4);
    float* vs  = (float*)alloc((size_t)N_NODES * 4);
    unsigned short* Wr16 = (unsigned short*)alloc((size_t)N_RELS * 64 * 2);
    float* Qr  = (float*)alloc((size_t)N_RELS * 64 * 4);
    float* wsr = (float*)alloc((size_t)N_RELS * 4);
    int* cnt_src   = (int*)alloc((size_t)N_NODES * 4);
    int* start_src = (int*)alloc((size_t)N_NODES * 4);
    float* bsum    = (float*)alloc((size_t)N_NODES * 4);
    int* cnts      = (int*)alloc((size_t)NROWS * 4);   // [0..499]=cnt_rel, [500..]=bucket_cnt
    int* starts    = (int*)alloc((size_t)NROWS * 4);
    int* blkhist   = (int*)alloc((size_t)NROWS * NB_E * 4);
    int* blkbase   = (int*)alloc((size_t)NROWS * NB_E * 4);
    int* stg_a     = (int*)alloc((size_t)N_EDGES * 4);
    int* stg_b     = (int*)alloc((size_t)N_EDGES * 4);
    int2* pay_src  = (int2*)alloc((size_t)N_EDGES * 8);
    float* pay_b   = (float*)alloc((size_t)N_EDGES * 4);
    int2* pay_rel  = (int2*)alloc((size_t)N_EDGES * 8);
    float* part    = (float*)alloc((size_t)N_RELS * RSUB * 128 * 4);

    int* cnt_rel    = cnts;
    int* bucket_cnt = cnts + N_RELS;

    k_zero<<<(NROWS + 255) / 256, 256, 0, stream>>>(cnts, NROWS);

    k_fold<<<65, 256, 0, stream>>>(W_ent, b_ent, W_relL, b_relL, W_rel2, b_rel2,
                                   W_fc, b_fc, Wcat, dcat, MW, MQ, dW, dQ);
    k_node<<<(N_NODES + 63) / 64, 256, 0, stream>>>(ent, Wcat, dcat, W_a, out, V16, us, vs);
    k_relproj<<<125, 256, 0, stream>>>(relE, MW, MQ, dW, dQ, W_a, Wr16, Qr, wsr);
    k_hist<<<NB_E, 256, 0, stream>>>(src, rel, cnt_rel, bucket_cnt, blkhist);
    k_scan_two<<<2, 256, 0, stream>>>(cnt_rel, bucket_cnt, starts);
    k_scan_relblk<<<(NROWS * 64 + 255) / 256, 256, 0, stream>>>(starts, blkhist, blkbase);
    k_scatter<<<NB_E, 256, 0, stream>>>(src, dst, rel, blkbase, pay_rel, stg_a, stg_b);
    k_sortb<<<NBKT, 256, 0, stream>>>(stg_a, stg_b, starts, bucket_cnt,
                                      us, vs, wsr, b_a,
                                      pay_src, pay_b, start_src, cnt_src, bsum);
    k_attn<<<(N_NODES + 15) / 16, 256, 0, stream>>>(pay_src, pay_b, start_src, cnt_src,
                                                    bsum, V16, Wr16, out, h8);
    k_relpool<<<N_RELS * RSUB, 256, 0, stream>>>(pay_rel, starts, cnt_rel, h8, part);
    k_relfin<<<(N_RELS * 64 + 255) / 256, 256, 0, stream>>>(part, cnt_rel, Qr, W_rel3,
                                                            b_rel3, out + (size_t)N_NODES * 64);
}

// Round 8
// 290.063 us; speedup vs baseline: 1.0457x; 1.0457x over previous
//
#include <hip/hip_runtime.h>
#include <hip/hip_fp16.h>
#include <math.h>

#define N_NODES 100000
#define N_RELS  500
#define DIM     64
#define N_EDGES 1000000
#define SLOPE   0.01f
#define RSUB    4       // blocks per relation in pooling
#define SC_EDGES 2048   // edges per block in hist/scatter partition
#define NB_E    489     // ceil(N_EDGES / SC_EDGES)
#define NBKT    196     // src buckets (src >> 9, 512 nodes each)
#define BSH     9
#define NROWS   (N_RELS + NBKT)   // 696 rows in blkhist/blkbase
#define BMAX    5632    // LDS slots per bucket in k_sortb

// bf16 pack/unpack (round-to-nearest-even)
__device__ __forceinline__ unsigned short f2bf(float f) {
    unsigned int u = __float_as_uint(f);
    u += 0x7FFFu + ((u >> 16) & 1u);
    return (unsigned short)(u >> 16);
}
__device__ __forceinline__ float bfl(unsigned int u) { return __uint_as_float(u << 16); }
__device__ __forceinline__ float bfh(unsigned int u) { return __uint_as_float(u & 0xFFFF0000u); }

// fp8 e5m2 pack/unpack. e5m2 == fp16 with mantissa truncated to 2 bits:
// decode is (byte<<8) reinterpreted as half; encode is f32->f16 RTNE then
// RTNE-round to the upper byte. Used ONLY for the relation-pooling shadow of
// h (mean over ~2000 edges + |W_rel3|<=0.072 attenuate the quant noise).
__device__ __forceinline__ unsigned int f2e5m2(float f) {
    __half h = __float2half_rn(f);
    unsigned short hu;
    __builtin_memcpy(&hu, &h, 2);
    unsigned int u = hu;
    u += 0x7Fu + ((u >> 8) & 1u);
    return (u >> 8) & 0xFFu;
}
__device__ __forceinline__ float e5d(unsigned int b) {
    unsigned short u = (unsigned short)(b << 8);
    __half h;
    __builtin_memcpy(&h, &u, 2);
    return __half2float(h);
}
__device__ __forceinline__ void acc8(float* a, unsigned int x, unsigned int y) {
    a[0] += e5d(x & 255u);         a[1] += e5d((x >> 8) & 255u);
    a[2] += e5d((x >> 16) & 255u); a[3] += e5d(x >> 24);
    a[4] += e5d(y & 255u);         a[5] += e5d((y >> 8) & 255u);
    a[6] += e5d((y >> 16) & 255u); a[7] += e5d(y >> 24);
}
__device__ __forceinline__ void acc16(float* a, uint4 w) {
    acc8(a, w.x, w.y);
    acc8(a + 8, w.z, w.w);
}

// ---------------------------------------------------------------------------
// K0: fold the small matrices.
// ---------------------------------------------------------------------------
__global__ void k_fold(const float* __restrict__ W_ent, const float* __restrict__ b_ent,
                       const float* __restrict__ W_relL, const float* __restrict__ b_relL,
                       const float* __restrict__ W_rel2, const float* __restrict__ b_rel2,
                       const float* __restrict__ W_fc, const float* __restrict__ b_fc,
                       float* __restrict__ Wcat, float* __restrict__ dcat,
                       float* __restrict__ MW, float* __restrict__ MQ,
                       float* __restrict__ dW, float* __restrict__ dQ) {
    int idx = blockIdx.x * 256 + threadIdx.x;
    if (idx < 8192) {
        int k = idx >> 7;
        int j2 = idx & 127;
        int jj = j2 & 63;
        int off = (j2 >> 6) * 64;
        float s = 0.f;
        for (int i = 0; i < 64; i++) s += W_fc[jj*192 + off + i] * W_ent[i*64 + k];
        Wcat[k*128 + j2] = s;
    } else if (idx < 12288) {
        int rem = idx - 8192;
        int j = rem >> 6, i = rem & 63;
        float s = 0.f;
        for (int k = 0; k < 64; k++) s += W_fc[j*192 + 128 + k] * W_relL[k*64 + i];
        MW[j*64 + i] = s;
    } else if (idx < 16384) {
        int rem = idx - 12288;
        int j = rem >> 6, i = rem & 63;
        float s = 0.f;
        for (int k = 0; k < 64; k++) s += W_rel2[j*64 + k] * W_relL[k*64 + i];
        MQ[j*64 + i] = s;
    } else if (idx < 16512) {
        int j2 = idx - 16384;
        int jj = j2 & 63;
        int off = (j2 >> 6) * 64;
        float s = 0.f;
        for (int i = 0; i < 64; i++) s += b_ent[i] * W_fc[jj*192 + off + i];
        dcat[j2] = s;
    } else if (idx < 16640) {
        int rem = idx - 16512;
        int vec = rem >> 6, j = rem & 63;
        if (vec == 0) {
            float s = b_fc[j];
            for (int k = 0; k < 64; k++) s += b_relL[k] * W_fc[j*192 + 128 + k];
            dW[j] = s;
        } else {
            float s = b_rel2[j];
            for (int k = 0; k < 64; k++) s += b_relL[k] * W_rel2[j*64 + k];
            dQ[j] = s;
        }
    }
}

// ---------------------------------------------------------------------------
// K1: per-node projections (LDS-tiled GEMM). U -> fp32 (output buffer);
// V -> bf16 shadow only.
// ---------------------------------------------------------------------------
__global__ __launch_bounds__(256) void k_node(const float* __restrict__ ent,
        const float* __restrict__ Wcat, const float* __restrict__ dcat,
        const float* __restrict__ W_a,
        float* __restrict__ Uout, unsigned short* __restrict__ V16,
        float* __restrict__ us, float* __restrict__ vs) {
    __shared__ float sA[64][68];
    __shared__ float sW[64][128];
    int t = threadIdx.x;
    int tile0 = blockIdx.x * 64;
    for (int i = t; i < 2048; i += 256)
        ((float4*)sW)[i] = ((const float4*)Wcat)[i];
    for (int f = t; f < 1024; f += 256) {
        int n = f >> 4, k4 = f & 15;
        float4 v4 = (tile0 + n < N_NODES)
            ? ((const float4*)(ent + (size_t)(tile0 + n) * 64))[k4]
            : make_float4(0.f, 0.f, 0.f, 0.f);
        *(float4*)&sA[n][k4 * 4] = v4;
    }
    __syncthreads();

    int ng = t >> 4;
    int jg = t & 15;
    int n0 = ng * 4;
    int j0 = jg * 8;

    float4 d0 = *(const float4*)(dcat + j0);
    float4 d1 = *(const float4*)(dcat + j0 + 4);
    float acc[4][8];
    #pragma unroll
    for (int a = 0; a < 4; a++) {
        acc[a][0] = d0.x; acc[a][1] = d0.y; acc[a][2] = d0.z; acc[a][3] = d0.w;
        acc[a][4] = d1.x; acc[a][5] = d1.y; acc[a][6] = d1.z; acc[a][7] = d1.w;
    }

    #pragma unroll 4
    for (int k = 0; k < 64; k++) {
        float4 w0 = *(const float4*)&sW[k][j0];
        float4 w1 = *(const float4*)&sW[k][j0 + 4];
        float e0 = sA[n0][k], e1 = sA[n0+1][k], e2 = sA[n0+2][k], e3 = sA[n0+3][k];
        float e[4] = {e0, e1, e2, e3};
        #pragma unroll
        for (int a = 0; a < 4; a++) {
            acc[a][0] += e[a] * w0.x; acc[a][1] += e[a] * w0.y;
            acc[a][2] += e[a] * w0.z; acc[a][3] += e[a] * w0.w;
            acc[a][4] += e[a] * w1.x; acc[a][5] += e[a] * w1.y;
            acc[a][6] += e[a] * w1.z; acc[a][7] += e[a] * w1.w;
        }
    }

    int jw = j0 & 63;
    float4 wa0 = *(const float4*)(W_a + jw);
    float4 wa1 = *(const float4*)(W_a + jw + 4);
    float part[4];
    #pragma unroll
    for (int a = 0; a < 4; a++) {
        part[a] = acc[a][0]*wa0.x + acc[a][1]*wa0.y + acc[a][2]*wa0.z + acc[a][3]*wa0.w
                + acc[a][4]*wa1.x + acc[a][5]*wa1.y + acc[a][6]*wa1.z + acc[a][7]*wa1.w;
    }
    #pragma unroll
    for (int m = 1; m <= 4; m <<= 1) {
        #pragma unroll
        for (int a = 0; a < 4; a++) part[a] += __shfl_xor(part[a], m, 64);
    }
    if ((jg & 7) == 0) {
        float* sv = (jg < 8) ? us : vs;
        #pragma unroll
        for (int a = 0; a < 4; a++)
            if (tile0 + n0 + a < N_NODES) sv[tile0 + n0 + a] = part[a];
    }

    #pragma unroll
    for (int a = 0; a < 4; a++) {
        int n = tile0 + n0 + a;
        if (n >= N_NODES) break;
        if (jg < 8) {
            float4 o0 = make_float4(acc[a][0], acc[a][1], acc[a][2], acc[a][3]);
            float4 o1 = make_float4(acc[a][4], acc[a][5], acc[a][6], acc[a][7]);
            float* base = Uout + (size_t)n * 64 + j0;
            *(float4*)(base) = o0;
            *(float4*)(base + 4) = o1;
        } else {
            uint4 pv;
            pv.x = (unsigned int)f2bf(acc[a][0]) | ((unsigned int)f2bf(acc[a][1]) << 16);
            pv.y = (unsigned int)f2bf(acc[a][2]) | ((unsigned int)f2bf(acc[a][3]) << 16);
            pv.z = (unsigned int)f2bf(acc[a][4]) | ((unsigned int)f2bf(acc[a][5]) << 16);
            pv.w = (unsigned int)f2bf(acc[a][6]) | ((unsigned int)f2bf(acc[a][7]) << 16);
            *(uint4*)(V16 + (size_t)n * 64 + (j0 - 64)) = pv;
        }
    }
}

// K2: per-relation projections. Wr -> bf16 shadow; Qr fp32; wsr fp32.
__global__ __launch_bounds__(256, 2) void k_relproj(const float* __restrict__ relE,
        const float* __restrict__ MW, const float* __restrict__ MQ,
        const float* __restrict__ dW, const float* __restrict__ dQ,
        const float* __restrict__ W_a,
        unsigned short* __restrict__ Wr16, float* __restrict__ Qr, float* __restrict__ wsr) {
    int lane = threadIdx.x & 63;
    int wv = threadIdx.x >> 6;
    float mw[64], mq[64];
    #pragma unroll
    for (int i = 0; i < 64; i++) { mw[i] = MW[lane*64 + i]; mq[i] = MQ[lane*64 + i]; }
    float dw = dW[lane], dq = dQ[lane], wa = W_a[lane];
    int r = blockIdx.x * 4 + wv;
    if (r >= N_RELS) return;
    float e = relE[(size_t)r * 64 + lane];
    float w = dw, q = dq;
    #pragma unroll
    for (int i = 0; i < 64; i++) {
        float ei = __shfl(e, i, 64);
        w += ei * mw[i];
        q += ei * mq[i];
    }
    Wr16[(size_t)r * 64 + lane] = f2bf(w);
    Qr[(size_t)r * 64 + lane] = q;
    float tw = w * wa;
    #pragma unroll
    for (int o = 32; o; o >>= 1) tw += __shfl_xor(tw, o, 64);
    if (lane == 0) wsr[r] = tw;
}

__global__ void k_zero(int* __restrict__ a, int n) {
    int g = blockIdx.x * 256 + threadIdx.x;
    if (g < n) a[g] = 0;
}

// ---------------------------------------------------------------------------
// K3: histogram (LDS hists: 500 rels + 196 src-buckets; transposed blkhist).
// ---------------------------------------------------------------------------
__global__ __launch_bounds__(256) void k_hist(const int* __restrict__ src, const int* __restrict__ rel,
        int* __restrict__ cnt_rel, int* __restrict__ bucket_cnt, int* __restrict__ blkhist) {
    __shared__ int lcntR[N_RELS];
    __shared__ int lcntS[NBKT];
    int t = threadIdx.x;
    for (int r = t; r < N_RELS; r += 256) lcntR[r] = 0;
    for (int b = t; b < NBKT; b += 256) lcntS[b] = 0;
    __syncthreads();
    int base = blockIdx.x * SC_EDGES;
    if (base + SC_EDGES <= N_EDGES) {
        int e0 = base + t * 8;
        int4 sa = *(const int4*)(src + e0);
        int4 sb = *(const int4*)(src + e0 + 4);
        int4 ra = *(const int4*)(rel + e0);
        int4 rb = *(const int4*)(rel + e0 + 4);
        atomicAdd(&lcntS[sa.x >> BSH], 1); atomicAdd(&lcntS[sa.y >> BSH], 1);
        atomicAdd(&lcntS[sa.z >> BSH], 1); atomicAdd(&lcntS[sa.w >> BSH], 1);
        atomicAdd(&lcntS[sb.x >> BSH], 1); atomicAdd(&lcntS[sb.y >> BSH], 1);
        atomicAdd(&lcntS[sb.z >> BSH], 1); atomicAdd(&lcntS[sb.w >> BSH], 1);
        atomicAdd(&lcntR[ra.x], 1); atomicAdd(&lcntR[ra.y], 1);
        atomicAdd(&lcntR[ra.z], 1); atomicAdd(&lcntR[ra.w], 1);
        atomicAdd(&lcntR[rb.x], 1); atomicAdd(&lcntR[rb.y], 1);
        atomicAdd(&lcntR[rb.z], 1); atomicAdd(&lcntR[rb.w], 1);
    } else {
        for (int g = base + t; g < N_EDGES; g += 256) {
            atomicAdd(&lcntS[src[g] >> BSH], 1);
            atomicAdd(&lcntR[rel[g]], 1);
        }
    }
    __syncthreads();
    for (int r = t; r < N_RELS; r += 256) {
        int c = lcntR[r];
        blkhist[(size_t)r * NB_E + blockIdx.x] = c;
        if (c) atomicAdd(&cnt_rel[r], c);
    }
    for (int b = t; b < NBKT; b += 256) {
        int c = lcntS[b];
        blkhist[(size_t)(N_RELS + b) * NB_E + blockIdx.x] = c;
        if (c) atomicAdd(&bucket_cnt[b], c);
    }
}

// K4a: two small exclusive scans (rels, buckets).
__global__ void k_scan_two(const int* __restrict__ cnt_rel, const int* __restrict__ bucket_cnt,
                           int* __restrict__ starts) {
    __shared__ int tot[256];
    int t = threadIdx.x;
    const int* cnt = blockIdx.x ? bucket_cnt : cnt_rel;
    int n = blockIdx.x ? NBKT : N_RELS;
    int* out = starts + (blockIdx.x ? N_RELS : 0);
    int myv[4];
    int mySum = 0;
    for (int q = 0; q < 4; q++) {
        int g = t * 4 + q;
        int v = (g < n) ? cnt[g] : 0;
        myv[q] = v; mySum += v;
    }
    tot[t] = mySum;
    __syncthreads();
    for (int o = 1; o < 256; o <<= 1) {
        int u = (t >= o) ? tot[t - o] : 0;
        __syncthreads();
        tot[t] += u;
        __syncthreads();
    }
    int run = tot[t] - mySum;
    for (int q = 0; q < 4; q++) {
        int g = t * 4 + q;
        if (g < n) out[g] = run;
        run += myv[q];
    }
}

// K4b: per-(row, block) bases; one wave per row.
__global__ __launch_bounds__(256) void k_scan_relblk(const int* __restrict__ starts,
        const int* __restrict__ blkhist, int* __restrict__ blkbase) {
    int lane = threadIdx.x & 63;
    int row = (blockIdx.x * 256 + threadIdx.x) >> 6;
    if (row >= NROWS) return;
    int run = starts[row];
    for (int base = 0; base < NB_E; base += 64) {
        int b = base + lane;
        int v = (b < NB_E) ? blkhist[(size_t)row * NB_E + b] : 0;
        int x = v;
        #pragma unroll
        for (int o = 1; o < 64; o <<= 1) {
            int y = __shfl_up(x, o, 64);
            if (lane >= o) x += y;
        }
        if (b < NB_E) blkbase[(size_t)row * NB_E + b] = run + (x - v);
        run += __shfl(x, 63, 64);
    }
}

// ---------------------------------------------------------------------------
// K5: pass-A scatter (no global atomics).
// ---------------------------------------------------------------------------
__global__ __launch_bounds__(256) void k_scatter(const int* __restrict__ src, const int* __restrict__ dst,
        const int* __restrict__ rel, const int* __restrict__ blkbase,
        int2* __restrict__ pay_rel, int* __restrict__ stg_a, int* __restrict__ stg_b) {
    __shared__ int lbaseR[N_RELS];
    __shared__ int loffR[N_RELS];
    __shared__ int lbaseS[NBKT];
    __shared__ int loffS[NBKT];
    int t = threadIdx.x;
    for (int r = t; r < N_RELS; r += 256) {
        lbaseR[r] = blkbase[(size_t)r * NB_E + blockIdx.x];
        loffR[r] = 0;
    }
    for (int b = t; b < NBKT; b += 256) {
        lbaseS[b] = blkbase[(size_t)(N_RELS + b) * NB_E + blockIdx.x];
        loffS[b] = 0;
    }
    __syncthreads();
    int base = blockIdx.x * SC_EDGES;
    if (base + SC_EDGES <= N_EDGES) {
        int e0 = base + t * 8;
        int4 sa = *(const int4*)(src + e0);
        int4 sb = *(const int4*)(src + e0 + 4);
        int4 da = *(const int4*)(dst + e0);
        int4 db = *(const int4*)(dst + e0 + 4);
        int4 ra = *(const int4*)(rel + e0);
        int4 rb = *(const int4*)(rel + e0 + 4);
        int s[8] = {sa.x, sa.y, sa.z, sa.w, sb.x, sb.y, sb.z, sb.w};
        int d[8] = {da.x, da.y, da.z, da.w, db.x, db.y, db.z, db.w};
        int r8[8] = {ra.x, ra.y, ra.z, ra.w, rb.x, rb.y, rb.z, rb.w};
        int p[8], q[8];
        #pragma unroll
        for (int j = 0; j < 8; j++) q[j] = lbaseR[r8[j]] + atomicAdd(&loffR[r8[j]], 1);
        #pragma unroll
        for (int j = 0; j < 8; j++) p[j] = lbaseS[s[j] >> BSH] + atomicAdd(&loffS[s[j] >> BSH], 1);
        #pragma unroll
        for (int j = 0; j < 8; j++) pay_rel[q[j]] = make_int2(s[j], d[j]);
        #pragma unroll
        for (int j = 0; j < 8; j++) stg_a[p[j]] = d[j];
        #pragma unroll
        for (int j = 0; j < 8; j++) stg_b[p[j]] = ((s[j] & 511) << 9) | r8[j];
    } else {
        for (int g = base + t; g < N_EDGES; g += 256) {
            int s = src[g], d = dst[g], r = rel[g];
            int q = lbaseR[r] + atomicAdd(&loffR[r], 1);
            pay_rel[q] = make_int2(s, d);
            int sb2 = s >> BSH;
            int p = lbaseS[sb2] + atomicAdd(&loffS[sb2], 1);
            stg_a[p] = d;
            stg_b[p] = ((s & 511) << 9) | r;
        }
    }
}

// ---------------------------------------------------------------------------
// K5b: pass-B bucket counting sort -> pay_src + start/cnt_src. Also computes
// per-edge attention weight b = exp(leaky(us+vs+wsr+ba)) -> pay_b (coalesced)
// and per-node bsum (LDS float atomics) -> bsum_arr.
// ---------------------------------------------------------------------------
__global__ __launch_bounds__(256) void k_sortb(const int* __restrict__ stg_a,
        const int* __restrict__ stg_b, const int* __restrict__ starts,
        const int* __restrict__ bucket_cnt,
        const float* __restrict__ us, const float* __restrict__ vs,
        const float* __restrict__ wsr, const float* __restrict__ b_a_p,
        int2* __restrict__ pay_src, float* __restrict__ pay_b,
        int* __restrict__ start_src, int* __restrict__ cnt_src,
        float* __restrict__ bsum_arr) {
    __shared__ int hist[512];
    __shared__ int lstart[512];
    __shared__ int loff[512];
    __shared__ int tot[256];
    __shared__ float lbsum[512];
    __shared__ int2 lpay[BMAX];
    int bkt = blockIdx.x;
    int base = starts[N_RELS + bkt];
    int n = bucket_cnt[bkt];
    int t = threadIdx.x;
    float ba = b_a_p[0];
    hist[t] = 0; hist[t + 256] = 0;
    lbsum[t] = 0.f; lbsum[t + 256] = 0.f;
    __syncthreads();
    for (int i = t; i < n; i += 256)
        atomicAdd(&hist[stg_b[base + i] >> 9], 1);
    __syncthreads();
    int v0 = hist[t * 2], v1 = hist[t * 2 + 1];
    int mySum = v0 + v1;
    tot[t] = mySum;
    __syncthreads();
    for (int o = 1; o < 256; o <<= 1) {
        int u = (t >= o) ? tot[t - o] : 0;
        __syncthreads();
        tot[t] += u;
        __syncthreads();
    }
    int run = tot[t] - mySum;
    lstart[t * 2] = run;
    lstart[t * 2 + 1] = run + v0;
    loff[t * 2] = 0;
    loff[t * 2 + 1] = 0;
    int node0 = bkt * 512 + t * 2;
    if (node0 < N_NODES) { start_src[node0] = base + run; cnt_src[node0] = v0; }
    if (node0 + 1 < N_NODES) { start_src[node0 + 1] = base + run + v0; cnt_src[node0 + 1] = v1; }
    __syncthreads();
    bool fits = (n <= BMAX);
    for (int i = t; i < n; i += 256) {
        int bb = stg_b[base + i];
        int d = stg_a[base + i];
        int lo = bb >> 9;
        int pos = lstart[lo] + atomicAdd(&loff[lo], 1);
        if (fits) {
            lpay[pos] = make_int2(d, bb);
        } else {
            int r = bb & 511;
            int s = bkt * 512 + lo;
            float t0 = us[s] + vs[d] + wsr[r] + ba;
            t0 = t0 > 0.f ? t0 : SLOPE * t0;
            float b = expf(t0);
            pay_src[base + pos] = make_int2(d, r);
            pay_b[base + pos] = b;
            atomicAdd(&lbsum[lo], b);
        }
    }
    __syncthreads();
    if (fits) {
        for (int i = t; i < n; i += 256) {
            int2 pr = lpay[i];
            int bb = pr.y;
            int lo = bb >> 9;
            int r = bb & 511;
            int s = bkt * 512 + lo;
            float t0 = us[s] + vs[pr.x] + wsr[r] + ba;
            t0 = t0 > 0.f ? t0 : SLOPE * t0;
            float b = expf(t0);
            pay_src[base + i] = make_int2(pr.x, r);
            pay_b[base + i] = b;
            atomicAdd(&lbsum[lo], b);
        }
        __syncthreads();
    }
    if (node0 < N_NODES) bsum_arr[node0] = lbsum[t * 2];
    if (node0 + 1 < N_NODES) bsum_arr[node0 + 1] = lbsum[t * 2 + 1];
}

// ---------------------------------------------------------------------------
// K6: aggregation. 4 nodes per wave (16 lanes each, 8 lanes per edge row);
// b/bsum precomputed; payload broadcast via same-address loads; dual-edge
// unroll = 4 gather rows in flight per lane. h shadow emitted as fp8 e5m2.
// ---------------------------------------------------------------------------
__global__ __launch_bounds__(256) void k_attn(const int2* __restrict__ pay,
        const float* __restrict__ pay_b,
        const int* __restrict__ start_src, const int* __restrict__ cnt_src,
        const float* __restrict__ bsum_arr,
        const unsigned short* __restrict__ V16, const unsigned short* __restrict__ Wr16,
        float* __restrict__ h, unsigned char* __restrict__ h8) {
    int lane = threadIdx.x & 63;
    int wv = threadIdx.x >> 6;
    int quarter = lane >> 4;
    int lq = lane & 15;
    int slot = lq >> 3;      // 0/1: even/odd edge stream
    int li = lq & 7;         // dim octet
    int n = blockIdx.x * 16 + wv * 4 + quarter;
    if (n >= N_NODES) return;
    int st = start_src[n];
    int cnt = cnt_src[n];
    if (cnt == 0) {
        if (lq < 8) {
            float* hp = h + (size_t)n * 64 + lq * 8;
            *(float4*)hp = make_float4(0.f, 0.f, 0.f, 0.f);
            *(float4*)(hp + 4) = make_float4(0.f, 0.f, 0.f, 0.f);
            *(uint2*)(h8 + (size_t)n * 64 + lq * 8) = make_uint2(0u, 0u);
        }
        return;
    }
    float inv = 1.f / bsum_arr[n];
    float a[8] = {0.f, 0.f, 0.f, 0.f, 0.f, 0.f, 0.f, 0.f};
    for (int e = slot; e < cnt; e += 4) {
        int eB = e + 2;
        bool vB = eB < cnt;
        int eBc = vB ? eB : e;
        float bA = pay_b[st + e];
        float bB = vB ? pay_b[st + eB] : 0.f;
        int2 pA = pay[st + e];
        int2 pB = pay[st + eBc];
        uint4 vvA = *(const uint4*)(V16 + (size_t)pA.x * 64 + li * 8);
        uint4 wwA = *(const uint4*)(Wr16 + (size_t)pA.y * 64 + li * 8);
        uint4 vvB = *(const uint4*)(V16 + (size_t)pB.x * 64 + li * 8);
        uint4 wwB = *(const uint4*)(Wr16 + (size_t)pB.y * 64 + li * 8);
        a[0] += bA * (bfl(vvA.x) + bfl(wwA.x)) + bB * (bfl(vvB.x) + bfl(wwB.x));
        a[1] += bA * (bfh(vvA.x) + bfh(wwA.x)) + bB * (bfh(vvB.x) + bfh(wwB.x));
        a[2] += bA * (bfl(vvA.y) + bfl(wwA.y)) + bB * (bfl(vvB.y) + bfl(wwB.y));
        a[3] += bA * (bfh(vvA.y) + bfh(wwA.y)) + bB * (bfh(vvB.y) + bfh(wwB.y));
        a[4] += bA * (bfl(vvA.z) + bfl(wwA.z)) + bB * (bfl(vvB.z) + bfl(wwB.z));
        a[5] += bA * (bfh(vvA.z) + bfh(wwA.z)) + bB * (bfh(vvB.z) + bfh(wwB.z));
        a[6] += bA * (bfl(vvA.w) + bfl(wwA.w)) + bB * (bfl(vvB.w) + bfl(wwB.w));
        a[7] += bA * (bfh(vvA.w) + bfh(wwA.w)) + bB * (bfh(vvB.w) + bfh(wwB.w));
    }
    #pragma unroll
    for (int d = 0; d < 8; d++) a[d] += __shfl_xor(a[d], 8, 64);
    if (slot == 0) {
        float* hp = h + (size_t)n * 64 + li * 8;
        float o[8];
        #pragma unroll
        for (int d = 0; d < 8; d++) o[d] = hp[d] + a[d] * inv;
        *(float4*)hp = make_float4(o[0], o[1], o[2], o[3]);
        *(float4*)(hp + 4) = make_float4(o[4], o[5], o[6], o[7]);
        uint2 p8;
        p8.x = f2e5m2(o[0]) | (f2e5m2(o[1]) << 8) | (f2e5m2(o[2]) << 16) | (f2e5m2(o[3]) << 24);
        p8.y = f2e5m2(o[4]) | (f2e5m2(o[5]) << 8) | (f2e5m2(o[6]) << 16) | (f2e5m2(o[7]) << 24);
        *(uint2*)(h8 + (size_t)n * 64 + li * 8) = p8;
    }
}

// ---------------------------------------------------------------------------
// K7: relation pooling over fp8 h8. 4 lanes per 64 B row (uint4 = 16 B/lane),
// 6 gather streams (192 edges per block-iteration, 96 rows in flight per wave
// before first consume), cross-iteration pay prefetch, shuffle-based reduce.
// Lane map: li = t&3 (row quarter), side = (t>>2)&1 (src/dst), j = t>>3.
// ---------------------------------------------------------------------------
#define RP_STREAMS 6
__global__ __launch_bounds__(256) void k_relpool(const int2* __restrict__ pay,
        const int* __restrict__ start_rel, const int* __restrict__ cnt_rel,
        const unsigned char* __restrict__ h8, float* __restrict__ acc_rel) {
    int r = blockIdx.x / RSUB;
    int sub = blockIdx.x % RSUB;
    int st = start_rel[r];
    int cnt = cnt_rel[r];
    int t = threadIdx.x;
    int li = t & 3;           // 16 B quarter of the 64 B row
    int side = (t >> 2) & 1;  // 0=src, 1=dst
    int j = t >> 3;           // 0..31 edge slot within block

    int chunk = (cnt + RSUB - 1) / RSUB;
    int k0 = sub * chunk;
    int k1 = min(k0 + chunk, cnt);
    int len = k1 - k0;

    float a[16];
    #pragma unroll
    for (int d = 0; d < 16; d++) a[d] = 0.f;

    if (len > 0) {
        const int2* pp = pay + st + k0;
        int m[RP_STREAMS]; bool v[RP_STREAMS]; int2 p[RP_STREAMS];
        #pragma unroll
        for (int s = 0; s < RP_STREAMS; s++) {
            m[s] = j + s * 32;
            v[s] = m[s] < len;
            p[s] = v[s] ? pp[m[s]] : make_int2(0, 0);
        }
        for (int base = 0; base < len; base += 32 * RP_STREAMS) {
            // issue all gathers (16 scattered 64 B rows per VMEM instr)
            uint4 hv[RP_STREAMS];
            #pragma unroll
            for (int s = 0; s < RP_STREAMS; s++) {
                int idx = side ? p[s].y : p[s].x;
                hv[s] = *(const uint4*)(h8 + (size_t)idx * 64 + li * 16);
            }
            // prefetch next iteration's pay while gathers are in flight
            int mn[RP_STREAMS]; bool vn[RP_STREAMS]; int2 pn[RP_STREAMS];
            #pragma unroll
            for (int s = 0; s < RP_STREAMS; s++) {
                mn[s] = m[s] + 32 * RP_STREAMS;
                vn[s] = mn[s] < len;
                pn[s] = vn[s] ? pp[mn[s]] : make_int2(0, 0);
            }
            #pragma unroll
            for (int s = 0; s < RP_STREAMS; s++) if (v[s]) acc16(a, hv[s]);
            #pragma unroll
            for (int s = 0; s < RP_STREAMS; s++) { m[s] = mn[s]; v[s] = vn[s]; p[s] = pn[s]; }
        }
    }

    // wave reduce over the 8 j-slots in this wave (lane bits 3,4,5)
    #pragma unroll
    for (int d = 0; d < 16; d++) {
        a[d] += __shfl_xor(a[d], 8, 64);
        a[d] += __shfl_xor(a[d], 16, 64);
        a[d] += __shfl_xor(a[d], 32, 64);
    }

    // cross-wave reduce via tiny LDS (2 KB), then 128 atomics per block
    __shared__ float red[4][8][16];
    int wv = t >> 6;
    int lane = t & 63;
    if (lane < 8) {
        #pragma unroll
        for (int d = 0; d < 16; d++) red[wv][lane][d] = a[d];
    }
    __syncthreads();
    if (t < 128) {
        int sl = t >> 4;   // (side<<2)|li
        int d = t & 15;
        float s = red[0][sl][d] + red[1][sl][d] + red[2][sl][d] + red[3][sl][d];
        int sd = sl >> 2;
        int li2 = sl & 3;
        atomicAdd(&acc_rel[r * 128 + sd * 64 + li2 * 16 + d], s);
    }
}

// K8: mean + h_rel = mean @ W_rel3.T + b_rel3
__global__ void k_relfin(const float* __restrict__ acc_rel, const int* __restrict__ cnt_rel,
                         const float* __restrict__ Qr, const float* __restrict__ W_rel3,
                         const float* __restrict__ b_rel3, float* __restrict__ out) {
    int g = blockIdx.x * 256 + threadIdx.x;
    if (g >= N_RELS * 64) return;
    int r = g >> 6;
    int j = g & 63;
    int cnt = cnt_rel[r];
    float invc = 1.f / (float)(cnt > 0 ? cnt : 1);
    float s = b_rel3[j];
    for (int k = 0; k < 128; k++) s += acc_rel[r * 128 + k] * invc * W_rel3[j * 192 + k];
    if (cnt > 0)
        for (int k = 0; k < 64; k++) s += Qr[r * 64 + k] * W_rel3[j * 192 + 128 + k];
    out[g] = s;
}

extern "C" void kernel_launch(void* const* d_in, const int* in_sizes, int n_in,
                              void* d_out, int out_size, void* d_ws, size_t ws_size,
                              hipStream_t stream) {
    const float* ent    = (const float*)d_in[0];
    const float* relE   = (const float*)d_in[1];
    const float* W_ent  = (const float*)d_in[2];
    const float* b_ent  = (const float*)d_in[3];
    const float* W_relL = (const float*)d_in[4];
    const float* b_relL = (const float*)d_in[5];
    const float* W_rel2 = (const float*)d_in[6];
    const float* b_rel2 = (const float*)d_in[7];
    const float* W_rel3 = (const float*)d_in[8];
    const float* b_rel3 = (const float*)d_in[9];
    const float* W_a    = (const float*)d_in[10];
    const float* b_a    = (const float*)d_in[11];
    const float* W_fc   = (const float*)d_in[12];
    const float* b_fc   = (const float*)d_in[13];
    const int* src = (const int*)d_in[14];
    const int* dst = (const int*)d_in[15];
    const int* rel = (const int*)d_in[16];
    float* out = (float*)d_out;

    char* ws = (char*)d_ws;
    size_t off = 0;
    auto alloc = [&](size_t bytes) -> void* {
        void* p = ws + off;
        off += (bytes + 255) & ~(size_t)255;
        return p;
    };
    float* Wcat = (float*)alloc(8192 * 4);
    float* dcat = (float*)alloc(128 * 4);
    float* MW  = (float*)alloc(4096 * 4);
    float* MQ  = (float*)alloc(4096 * 4);
    float* dW  = (float*)alloc(64 * 4);
    float* dQ  = (float*)alloc(64 * 4);
    unsigned short* V16 = (unsigned short*)alloc((size_t)N_NODES * 64 * 2);
    unsigned char* h8 = (unsigned char*)alloc((size_t)N_NODES * 64);
    float* us  = (float*)alloc((size_t)N_NODES * 4);
    float* vs  = (float*)alloc((size_t)N_NODES * 4);
    unsigned short* Wr16 = (unsigned short*)alloc((size_t)N_RELS * 64 * 2);
    float* Qr  = (float*)alloc((size_t)N_RELS * 64 * 4);
    float* wsr = (float*)alloc((size_t)N_RELS * 4);
    int* cnt_src   = (int*)alloc((size_t)N_NODES * 4);
    int* start_src = (int*)alloc((size_t)N_NODES * 4);
    float* bsum    = (float*)alloc((size_t)N_NODES * 4);
    int* cnts      = (int*)alloc((size_t)NROWS * 4);   // [0..499]=cnt_rel, [500..]=bucket_cnt
    int* starts    = (int*)alloc((size_t)NROWS * 4);
    int* blkhist   = (int*)alloc((size_t)NROWS * NB_E * 4);
    int* blkbase   = (int*)alloc((size_t)NROWS * NB_E * 4);
    int* stg_a     = (int*)alloc((size_t)N_EDGES * 4);
    int* stg_b     = (int*)alloc((size_t)N_EDGES * 4);
    int2* pay_src  = (int2*)alloc((size_t)N_EDGES * 8);
    float* pay_b   = (float*)alloc((size_t)N_EDGES * 4);
    int2* pay_rel  = (int2*)alloc((size_t)N_EDGES * 8);
    float* acc_rel = (float*)alloc((size_t)N_RELS * 128 * 4);

    int* cnt_rel    = cnts;
    int* bucket_cnt = cnts + N_RELS;

    k_zero<<<(NROWS + 255) / 256, 256, 0, stream>>>(cnts, NROWS);
    k_zero<<<(N_RELS * 128 + 255) / 256, 256, 0, stream>>>((int*)acc_rel, N_RELS * 128);

    k_fold<<<65, 256, 0, stream>>>(W_ent, b_ent, W_relL, b_relL, W_rel2, b_rel2,
                                   W_fc, b_fc, Wcat, dcat, MW, MQ, dW, dQ);
    k_node<<<(N_NODES + 63) / 64, 256, 0, stream>>>(ent, Wcat, dcat, W_a, out, V16, us, vs);
    k_relproj<<<125, 256, 0, stream>>>(relE, MW, MQ, dW, dQ, W_a, Wr16, Qr, wsr);
    k_hist<<<NB_E, 256, 0, stream>>>(src, rel, cnt_rel, bucket_cnt, blkhist);
    k_scan_two<<<2, 256, 0, stream>>>(cnt_rel, bucket_cnt, starts);
    k_scan_relblk<<<(NROWS * 64 + 255) / 256, 256, 0, stream>>>(starts, blkhist, blkbase);
    k_scatter<<<NB_E, 256, 0, stream>>>(src, dst, rel, blkbase, pay_rel, stg_a, stg_b);
    k_sortb<<<NBKT, 256, 0, stream>>>(stg_a, stg_b, starts, bucket_cnt,
                                      us, vs, wsr, b_a,
                                      pay_src, pay_b, start_src, cnt_src, bsum);
    k_attn<<<(N_NODES + 15) / 16, 256, 0, stream>>>(pay_src, pay_b, start_src, cnt_src,
                                                    bsum, V16, Wr16, out, h8);
    k_relpool<<<N_RELS * RSUB, 256, 0, stream>>>(pay_rel, starts, cnt_rel, h8, acc_rel);
    k_relfin<<<(N_RELS * 64 + 255) / 256, 256, 0, stream>>>(acc_rel, cnt_rel, Qr, W_rel3,
                                                            b_rel3, out + (size_t)N_NODES * 64);
}

// Round 9
// 288.677 us; speedup vs baseline: 1.0508x; 1.0048x over previous
//
#include <hip/hip_runtime.h>
#include <hip/hip_fp16.h>
#include <math.h>

#define N_NODES 100000
#define N_RELS  500
#define DIM     64
#define N_EDGES 1000000
#define SLOPE   0.01f
#define RSUB    4       // blocks per relation in pooling
#define SC_EDGES 2048   // edges per block in hist/scatter partition
#define NB_E    489     // ceil(N_EDGES / SC_EDGES)
#define NBKT    196     // src buckets (src >> 9, 512 nodes each)
#define BSH     9
#define NROWS   (N_RELS + NBKT)   // 696 rows in blkhist/blkbase
#define BMAX    5632    // LDS slots per bucket in k_sortb

// bf16 pack/unpack (round-to-nearest-even)
__device__ __forceinline__ unsigned short f2bf(float f) {
    unsigned int u = __float_as_uint(f);
    u += 0x7FFFu + ((u >> 16) & 1u);
    return (unsigned short)(u >> 16);
}
__device__ __forceinline__ float bfl(unsigned int u) { return __uint_as_float(u << 16); }
__device__ __forceinline__ float bfh(unsigned int u) { return __uint_as_float(u & 0xFFFF0000u); }

// fp8 e5m2 pack/unpack. e5m2 == fp16 with mantissa truncated to 2 bits:
// decode is (byte<<8) reinterpreted as half; encode is f32->f16 RTNE then
// RTNE-round to the upper byte. Used ONLY for the relation-pooling shadow of
// h (mean over ~2000 edges + |W_rel3|<=0.072 attenuate the quant noise).
__device__ __forceinline__ unsigned int f2e5m2(float f) {
    __half h = __float2half_rn(f);
    unsigned short hu;
    __builtin_memcpy(&hu, &h, 2);
    unsigned int u = hu;
    u += 0x7Fu + ((u >> 8) & 1u);
    return (u >> 8) & 0xFFu;
}
__device__ __forceinline__ float e5d(unsigned int b) {
    unsigned short u = (unsigned short)(b << 8);
    __half h;
    __builtin_memcpy(&h, &u, 2);
    return __half2float(h);
}
__device__ __forceinline__ void acc8(float* a, unsigned int x, unsigned int y) {
    a[0] += e5d(x & 255u);         a[1] += e5d((x >> 8) & 255u);
    a[2] += e5d((x >> 16) & 255u); a[3] += e5d(x >> 24);
    a[4] += e5d(y & 255u);         a[5] += e5d((y >> 8) & 255u);
    a[6] += e5d((y >> 16) & 255u); a[7] += e5d(y >> 24);
}
__device__ __forceinline__ void acc16(float* a, uint4 w) {
    acc8(a, w.x, w.y);
    acc8(a + 8, w.z, w.w);
}

// ---------------------------------------------------------------------------
// K0: fold the small matrices.
// ---------------------------------------------------------------------------
__global__ void k_fold(const float* __restrict__ W_ent, const float* __restrict__ b_ent,
                       const float* __restrict__ W_relL, const float* __restrict__ b_relL,
                       const float* __restrict__ W_rel2, const float* __restrict__ b_rel2,
                       const float* __restrict__ W_fc, const float* __restrict__ b_fc,
                       float* __restrict__ Wcat, float* __restrict__ dcat,
                       float* __restrict__ MW, float* __restrict__ MQ,
                       float* __restrict__ dW, float* __restrict__ dQ) {
    int idx = blockIdx.x * 256 + threadIdx.x;
    if (idx < 8192) {
        int k = idx >> 7;
        int j2 = idx & 127;
        int jj = j2 & 63;
        int off = (j2 >> 6) * 64;
        float s = 0.f;
        for (int i = 0; i < 64; i++) s += W_fc[jj*192 + off + i] * W_ent[i*64 + k];
        Wcat[k*128 + j2] = s;
    } else if (idx < 12288) {
        int rem = idx - 8192;
        int j = rem >> 6, i = rem & 63;
        float s = 0.f;
        for (int k = 0; k < 64; k++) s += W_fc[j*192 + 128 + k] * W_relL[k*64 + i];
        MW[j*64 + i] = s;
    } else if (idx < 16384) {
        int rem = idx - 12288;
        int j = rem >> 6, i = rem & 63;
        float s = 0.f;
        for (int k = 0; k < 64; k++) s += W_rel2[j*64 + k] * W_relL[k*64 + i];
        MQ[j*64 + i] = s;
    } else if (idx < 16512) {
        int j2 = idx - 16384;
        int jj = j2 & 63;
        int off = (j2 >> 6) * 64;
        float s = 0.f;
        for (int i = 0; i < 64; i++) s += b_ent[i] * W_fc[jj*192 + off + i];
        dcat[j2] = s;
    } else if (idx < 16640) {
        int rem = idx - 16512;
        int vec = rem >> 6, j = rem & 63;
        if (vec == 0) {
            float s = b_fc[j];
            for (int k = 0; k < 64; k++) s += b_relL[k] * W_fc[j*192 + 128 + k];
            dW[j] = s;
        } else {
            float s = b_rel2[j];
            for (int k = 0; k < 64; k++) s += b_relL[k] * W_rel2[j*64 + k];
            dQ[j] = s;
        }
    }
}

// ---------------------------------------------------------------------------
// K1: per-node projections (LDS-tiled GEMM). U -> fp32 (output buffer);
// V -> bf16 shadow only.
// ---------------------------------------------------------------------------
__global__ __launch_bounds__(256) void k_node(const float* __restrict__ ent,
        const float* __restrict__ Wcat, const float* __restrict__ dcat,
        const float* __restrict__ W_a,
        float* __restrict__ Uout, unsigned short* __restrict__ V16,
        float* __restrict__ us, float* __restrict__ vs) {
    __shared__ float sA[64][68];
    __shared__ float sW[64][128];
    int t = threadIdx.x;
    int tile0 = blockIdx.x * 64;
    for (int i = t; i < 2048; i += 256)
        ((float4*)sW)[i] = ((const float4*)Wcat)[i];
    for (int f = t; f < 1024; f += 256) {
        int n = f >> 4, k4 = f & 15;
        float4 v4 = (tile0 + n < N_NODES)
            ? ((const float4*)(ent + (size_t)(tile0 + n) * 64))[k4]
            : make_float4(0.f, 0.f, 0.f, 0.f);
        *(float4*)&sA[n][k4 * 4] = v4;
    }
    __syncthreads();

    int ng = t >> 4;
    int jg = t & 15;
    int n0 = ng * 4;
    int j0 = jg * 8;

    float4 d0 = *(const float4*)(dcat + j0);
    float4 d1 = *(const float4*)(dcat + j0 + 4);
    float acc[4][8];
    #pragma unroll
    for (int a = 0; a < 4; a++) {
        acc[a][0] = d0.x; acc[a][1] = d0.y; acc[a][2] = d0.z; acc[a][3] = d0.w;
        acc[a][4] = d1.x; acc[a][5] = d1.y; acc[a][6] = d1.z; acc[a][7] = d1.w;
    }

    #pragma unroll 4
    for (int k = 0; k < 64; k++) {
        float4 w0 = *(const float4*)&sW[k][j0];
        float4 w1 = *(const float4*)&sW[k][j0 + 4];
        float e0 = sA[n0][k], e1 = sA[n0+1][k], e2 = sA[n0+2][k], e3 = sA[n0+3][k];
        float e[4] = {e0, e1, e2, e3};
        #pragma unroll
        for (int a = 0; a < 4; a++) {
            acc[a][0] += e[a] * w0.x; acc[a][1] += e[a] * w0.y;
            acc[a][2] += e[a] * w0.z; acc[a][3] += e[a] * w0.w;
            acc[a][4] += e[a] * w1.x; acc[a][5] += e[a] * w1.y;
            acc[a][6] += e[a] * w1.z; acc[a][7] += e[a] * w1.w;
        }
    }

    int jw = j0 & 63;
    float4 wa0 = *(const float4*)(W_a + jw);
    float4 wa1 = *(const float4*)(W_a + jw + 4);
    float part[4];
    #pragma unroll
    for (int a = 0; a < 4; a++) {
        part[a] = acc[a][0]*wa0.x + acc[a][1]*wa0.y + acc[a][2]*wa0.z + acc[a][3]*wa0.w
                + acc[a][4]*wa1.x + acc[a][5]*wa1.y + acc[a][6]*wa1.z + acc[a][7]*wa1.w;
    }
    #pragma unroll
    for (int m = 1; m <= 4; m <<= 1) {
        #pragma unroll
        for (int a = 0; a < 4; a++) part[a] += __shfl_xor(part[a], m, 64);
    }
    if ((jg & 7) == 0) {
        float* sv = (jg < 8) ? us : vs;
        #pragma unroll
        for (int a = 0; a < 4; a++)
            if (tile0 + n0 + a < N_NODES) sv[tile0 + n0 + a] = part[a];
    }

    #pragma unroll
    for (int a = 0; a < 4; a++) {
        int n = tile0 + n0 + a;
        if (n >= N_NODES) break;
        if (jg < 8) {
            float4 o0 = make_float4(acc[a][0], acc[a][1], acc[a][2], acc[a][3]);
            float4 o1 = make_float4(acc[a][4], acc[a][5], acc[a][6], acc[a][7]);
            float* base = Uout + (size_t)n * 64 + j0;
            *(float4*)(base) = o0;
            *(float4*)(base + 4) = o1;
        } else {
            uint4 pv;
            pv.x = (unsigned int)f2bf(acc[a][0]) | ((unsigned int)f2bf(acc[a][1]) << 16);
            pv.y = (unsigned int)f2bf(acc[a][2]) | ((unsigned int)f2bf(acc[a][3]) << 16);
            pv.z = (unsigned int)f2bf(acc[a][4]) | ((unsigned int)f2bf(acc[a][5]) << 16);
            pv.w = (unsigned int)f2bf(acc[a][6]) | ((unsigned int)f2bf(acc[a][7]) << 16);
            *(uint4*)(V16 + (size_t)n * 64 + (j0 - 64)) = pv;
        }
    }
}

// K2: per-relation projections. Wr -> bf16 shadow; Qr fp32; wsr fp32.
__global__ __launch_bounds__(256, 2) void k_relproj(const float* __restrict__ relE,
        const float* __restrict__ MW, const float* __restrict__ MQ,
        const float* __restrict__ dW, const float* __restrict__ dQ,
        const float* __restrict__ W_a,
        unsigned short* __restrict__ Wr16, float* __restrict__ Qr, float* __restrict__ wsr) {
    int lane = threadIdx.x & 63;
    int wv = threadIdx.x >> 6;
    float mw[64], mq[64];
    #pragma unroll
    for (int i = 0; i < 64; i++) { mw[i] = MW[lane*64 + i]; mq[i] = MQ[lane*64 + i]; }
    float dw = dW[lane], dq = dQ[lane], wa = W_a[lane];
    int r = blockIdx.x * 4 + wv;
    if (r >= N_RELS) return;
    float e = relE[(size_t)r * 64 + lane];
    float w = dw, q = dq;
    #pragma unroll
    for (int i = 0; i < 64; i++) {
        float ei = __shfl(e, i, 64);
        w += ei * mw[i];
        q += ei * mq[i];
    }
    Wr16[(size_t)r * 64 + lane] = f2bf(w);
    Qr[(size_t)r * 64 + lane] = q;
    float tw = w * wa;
    #pragma unroll
    for (int o = 32; o; o >>= 1) tw += __shfl_xor(tw, o, 64);
    if (lane == 0) wsr[r] = tw;
}

__global__ void k_zero(int* __restrict__ a, int n) {
    int g = blockIdx.x * 256 + threadIdx.x;
    if (g < n) a[g] = 0;
}

// ---------------------------------------------------------------------------
// K3: histogram (LDS hists: 500 rels + 196 src-buckets; transposed blkhist).
// ---------------------------------------------------------------------------
__global__ __launch_bounds__(256) void k_hist(const int* __restrict__ src, const int* __restrict__ rel,
        int* __restrict__ cnt_rel, int* __restrict__ bucket_cnt, int* __restrict__ blkhist) {
    __shared__ int lcntR[N_RELS];
    __shared__ int lcntS[NBKT];
    int t = threadIdx.x;
    for (int r = t; r < N_RELS; r += 256) lcntR[r] = 0;
    for (int b = t; b < NBKT; b += 256) lcntS[b] = 0;
    __syncthreads();
    int base = blockIdx.x * SC_EDGES;
    if (base + SC_EDGES <= N_EDGES) {
        int e0 = base + t * 8;
        int4 sa = *(const int4*)(src + e0);
        int4 sb = *(const int4*)(src + e0 + 4);
        int4 ra = *(const int4*)(rel + e0);
        int4 rb = *(const int4*)(rel + e0 + 4);
        atomicAdd(&lcntS[sa.x >> BSH], 1); atomicAdd(&lcntS[sa.y >> BSH], 1);
        atomicAdd(&lcntS[sa.z >> BSH], 1); atomicAdd(&lcntS[sa.w >> BSH], 1);
        atomicAdd(&lcntS[sb.x >> BSH], 1); atomicAdd(&lcntS[sb.y >> BSH], 1);
        atomicAdd(&lcntS[sb.z >> BSH], 1); atomicAdd(&lcntS[sb.w >> BSH], 1);
        atomicAdd(&lcntR[ra.x], 1); atomicAdd(&lcntR[ra.y], 1);
        atomicAdd(&lcntR[ra.z], 1); atomicAdd(&lcntR[ra.w], 1);
        atomicAdd(&lcntR[rb.x], 1); atomicAdd(&lcntR[rb.y], 1);
        atomicAdd(&lcntR[rb.z], 1); atomicAdd(&lcntR[rb.w], 1);
    } else {
        for (int g = base + t; g < N_EDGES; g += 256) {
            atomicAdd(&lcntS[src[g] >> BSH], 1);
            atomicAdd(&lcntR[rel[g]], 1);
        }
    }
    __syncthreads();
    for (int r = t; r < N_RELS; r += 256) {
        int c = lcntR[r];
        blkhist[(size_t)r * NB_E + blockIdx.x] = c;
        if (c) atomicAdd(&cnt_rel[r], c);
    }
    for (int b = t; b < NBKT; b += 256) {
        int c = lcntS[b];
        blkhist[(size_t)(N_RELS + b) * NB_E + blockIdx.x] = c;
        if (c) atomicAdd(&bucket_cnt[b], c);
    }
}

// K4a: two small exclusive scans (rels, buckets).
__global__ void k_scan_two(const int* __restrict__ cnt_rel, const int* __restrict__ bucket_cnt,
                           int* __restrict__ starts) {
    __shared__ int tot[256];
    int t = threadIdx.x;
    const int* cnt = blockIdx.x ? bucket_cnt : cnt_rel;
    int n = blockIdx.x ? NBKT : N_RELS;
    int* out = starts + (blockIdx.x ? N_RELS : 0);
    int myv[4];
    int mySum = 0;
    for (int q = 0; q < 4; q++) {
        int g = t * 4 + q;
        int v = (g < n) ? cnt[g] : 0;
        myv[q] = v; mySum += v;
    }
    tot[t] = mySum;
    __syncthreads();
    for (int o = 1; o < 256; o <<= 1) {
        int u = (t >= o) ? tot[t - o] : 0;
        __syncthreads();
        tot[t] += u;
        __syncthreads();
    }
    int run = tot[t] - mySum;
    for (int q = 0; q < 4; q++) {
        int g = t * 4 + q;
        if (g < n) out[g] = run;
        run += myv[q];
    }
}

// K4b: per-(row, block) bases; one wave per row.
__global__ __launch_bounds__(256) void k_scan_relblk(const int* __restrict__ starts,
        const int* __restrict__ blkhist, int* __restrict__ blkbase) {
    int lane = threadIdx.x & 63;
    int row = (blockIdx.x * 256 + threadIdx.x) >> 6;
    if (row >= NROWS) return;
    int run = starts[row];
    for (int base = 0; base < NB_E; base += 64) {
        int b = base + lane;
        int v = (b < NB_E) ? blkhist[(size_t)row * NB_E + b] : 0;
        int x = v;
        #pragma unroll
        for (int o = 1; o < 64; o <<= 1) {
            int y = __shfl_up(x, o, 64);
            if (lane >= o) x += y;
        }
        if (b < NB_E) blkbase[(size_t)row * NB_E + b] = run + (x - v);
        run += __shfl(x, 63, 64);
    }
}

// ---------------------------------------------------------------------------
// K5: pass-A scatter (no global atomics).
// ---------------------------------------------------------------------------
__global__ __launch_bounds__(256) void k_scatter(const int* __restrict__ src, const int* __restrict__ dst,
        const int* __restrict__ rel, const int* __restrict__ blkbase,
        int2* __restrict__ pay_rel, int* __restrict__ stg_a, int* __restrict__ stg_b) {
    __shared__ int lbaseR[N_RELS];
    __shared__ int loffR[N_RELS];
    __shared__ int lbaseS[NBKT];
    __shared__ int loffS[NBKT];
    int t = threadIdx.x;
    for (int r = t; r < N_RELS; r += 256) {
        lbaseR[r] = blkbase[(size_t)r * NB_E + blockIdx.x];
        loffR[r] = 0;
    }
    for (int b = t; b < NBKT; b += 256) {
        lbaseS[b] = blkbase[(size_t)(N_RELS + b) * NB_E + blockIdx.x];
        loffS[b] = 0;
    }
    __syncthreads();
    int base = blockIdx.x * SC_EDGES;
    if (base + SC_EDGES <= N_EDGES) {
        int e0 = base + t * 8;
        int4 sa = *(const int4*)(src + e0);
        int4 sb = *(const int4*)(src + e0 + 4);
        int4 da = *(const int4*)(dst + e0);
        int4 db = *(const int4*)(dst + e0 + 4);
        int4 ra = *(const int4*)(rel + e0);
        int4 rb = *(const int4*)(rel + e0 + 4);
        int s[8] = {sa.x, sa.y, sa.z, sa.w, sb.x, sb.y, sb.z, sb.w};
        int d[8] = {da.x, da.y, da.z, da.w, db.x, db.y, db.z, db.w};
        int r8[8] = {ra.x, ra.y, ra.z, ra.w, rb.x, rb.y, rb.z, rb.w};
        int p[8], q[8];
        #pragma unroll
        for (int j = 0; j < 8; j++) q[j] = lbaseR[r8[j]] + atomicAdd(&loffR[r8[j]], 1);
        #pragma unroll
        for (int j = 0; j < 8; j++) p[j] = lbaseS[s[j] >> BSH] + atomicAdd(&loffS[s[j] >> BSH], 1);
        #pragma unroll
        for (int j = 0; j < 8; j++) pay_rel[q[j]] = make_int2(s[j], d[j]);
        #pragma unroll
        for (int j = 0; j < 8; j++) stg_a[p[j]] = d[j];
        #pragma unroll
        for (int j = 0; j < 8; j++) stg_b[p[j]] = ((s[j] & 511) << 9) | r8[j];
    } else {
        for (int g = base + t; g < N_EDGES; g += 256) {
            int s = src[g], d = dst[g], r = rel[g];
            int q = lbaseR[r] + atomicAdd(&loffR[r], 1);
            pay_rel[q] = make_int2(s, d);
            int sb2 = s >> BSH;
            int p = lbaseS[sb2] + atomicAdd(&loffS[sb2], 1);
            stg_a[p] = d;
            stg_b[p] = ((s & 511) << 9) | r;
        }
    }
}

// ---------------------------------------------------------------------------
// K5b: pass-B bucket counting sort -> pay_src + start/cnt_src, plus per-edge
// attention weight b = exp(leaky(us+vs+wsr+ba)) -> pay_b (coalesced).
// 1024 threads/block: 16 waves/CU (grid is 196 blocks = 1 block/CU) for 4x
// TLP on the hist and placement passes. bsum moved to k_attn (deletes the
// 1M LDS float atomics -- r3/r4 measured those as serializing per-lane).
// ---------------------------------------------------------------------------
__global__ __launch_bounds__(1024) void k_sortb(const int* __restrict__ stg_a,
        const int* __restrict__ stg_b, const int* __restrict__ starts,
        const int* __restrict__ bucket_cnt,
        const float* __restrict__ us, const float* __restrict__ vs,
        const float* __restrict__ wsr, const float* __restrict__ b_a_p,
        int2* __restrict__ pay_src, float* __restrict__ pay_b,
        int* __restrict__ start_src, int* __restrict__ cnt_src) {
    __shared__ int hist[512];
    __shared__ int lstart[512];
    __shared__ int loff[512];
    __shared__ int tot[256];
    __shared__ int2 lpay[BMAX];
    int bkt = blockIdx.x;
    int base = starts[N_RELS + bkt];
    int n = bucket_cnt[bkt];
    int t = threadIdx.x;
    float ba = b_a_p[0];
    if (t < 512) hist[t] = 0;
    __syncthreads();
    for (int i = t; i < n; i += 1024)
        atomicAdd(&hist[stg_b[base + i] >> 9], 1);
    __syncthreads();
    int v0 = 0, v1 = 0, mySum = 0;
    if (t < 256) {
        v0 = hist[t * 2]; v1 = hist[t * 2 + 1];
        mySum = v0 + v1;
        tot[t] = mySum;
    }
    __syncthreads();
    for (int o = 1; o < 256; o <<= 1) {
        int u = (t < 256 && t >= o) ? tot[t - o] : 0;
        __syncthreads();
        if (t < 256) tot[t] += u;
        __syncthreads();
    }
    if (t < 256) {
        int run = tot[t] - mySum;
        lstart[t * 2] = run;
        lstart[t * 2 + 1] = run + v0;
        loff[t * 2] = 0;
        loff[t * 2 + 1] = 0;
        int node0 = bkt * 512 + t * 2;
        if (node0 < N_NODES) { start_src[node0] = base + run; cnt_src[node0] = v0; }
        if (node0 + 1 < N_NODES) { start_src[node0 + 1] = base + run + v0; cnt_src[node0 + 1] = v1; }
    }
    __syncthreads();
    bool fits = (n <= BMAX);
    for (int i = t; i < n; i += 1024) {
        int bb = stg_b[base + i];
        int d = stg_a[base + i];
        int lo = bb >> 9;
        int pos = lstart[lo] + atomicAdd(&loff[lo], 1);
        if (fits) {
            lpay[pos] = make_int2(d, bb);
        } else {
            int r = bb & 511;
            int s = bkt * 512 + lo;
            float t0 = us[s] + vs[d] + wsr[r] + ba;
            t0 = t0 > 0.f ? t0 : SLOPE * t0;
            pay_src[base + pos] = make_int2(d, r);
            pay_b[base + pos] = expf(t0);
        }
    }
    __syncthreads();
    if (fits) {
        for (int i = t; i < n; i += 1024) {
            int2 pr = lpay[i];
            int bb = pr.y;
            int lo = bb >> 9;
            int r = bb & 511;
            int s = bkt * 512 + lo;
            float t0 = us[s] + vs[pr.x] + wsr[r] + ba;
            t0 = t0 > 0.f ? t0 : SLOPE * t0;
            pay_src[base + i] = make_int2(pr.x, r);
            pay_b[base + i] = expf(t0);
        }
    }
}

// ---------------------------------------------------------------------------
// K6: aggregation. 4 nodes per wave (16 lanes each, 8 lanes per edge row);
// b precomputed; bsum accumulated IN-REGISTER here (pay_b is loaded anyway;
// folds into the existing shfl_xor(8) reduce -- replaces k_sortb's LDS float
// atomics + bsum_arr round trip). Dual-edge unroll = 4 gather rows in flight
// per lane. h shadow emitted as fp8 e5m2.
// ---------------------------------------------------------------------------
__global__ __launch_bounds__(256) void k_attn(const int2* __restrict__ pay,
        const float* __restrict__ pay_b,
        const int* __restrict__ start_src, const int* __restrict__ cnt_src,
        const unsigned short* __restrict__ V16, const unsigned short* __restrict__ Wr16,
        float* __restrict__ h, unsigned char* __restrict__ h8) {
    int lane = threadIdx.x & 63;
    int wv = threadIdx.x >> 6;
    int quarter = lane >> 4;
    int lq = lane & 15;
    int slot = lq >> 3;      // 0/1: even/odd edge stream
    int li = lq & 7;         // dim octet
    int n = blockIdx.x * 16 + wv * 4 + quarter;
    if (n >= N_NODES) return;
    int st = start_src[n];
    int cnt = cnt_src[n];
    if (cnt == 0) {
        if (lq < 8) {
            float* hp = h + (size_t)n * 64 + lq * 8;
            *(float4*)hp = make_float4(0.f, 0.f, 0.f, 0.f);
            *(float4*)(hp + 4) = make_float4(0.f, 0.f, 0.f, 0.f);
            *(uint2*)(h8 + (size_t)n * 64 + lq * 8) = make_uint2(0u, 0u);
        }
        return;
    }
    float a[8] = {0.f, 0.f, 0.f, 0.f, 0.f, 0.f, 0.f, 0.f};
    float bs = 0.f;
    for (int e = slot; e < cnt; e += 4) {
        int eB = e + 2;
        bool vB = eB < cnt;
        int eBc = vB ? eB : e;
        float bA = pay_b[st + e];
        float bB = vB ? pay_b[st + eB] : 0.f;
        int2 pA = pay[st + e];
        int2 pB = pay[st + eBc];
        uint4 vvA = *(const uint4*)(V16 + (size_t)pA.x * 64 + li * 8);
        uint4 wwA = *(const uint4*)(Wr16 + (size_t)pA.y * 64 + li * 8);
        uint4 vvB = *(const uint4*)(V16 + (size_t)pB.x * 64 + li * 8);
        uint4 wwB = *(const uint4*)(Wr16 + (size_t)pB.y * 64 + li * 8);
        bs += bA + bB;
        a[0] += bA * (bfl(vvA.x) + bfl(wwA.x)) + bB * (bfl(vvB.x) + bfl(wwB.x));
        a[1] += bA * (bfh(vvA.x) + bfh(wwA.x)) + bB * (bfh(vvB.x) + bfh(wwB.x));
        a[2] += bA * (bfl(vvA.y) + bfl(wwA.y)) + bB * (bfl(vvB.y) + bfl(wwB.y));
        a[3] += bA * (bfh(vvA.y) + bfh(wwA.y)) + bB * (bfh(vvB.y) + bfh(wwB.y));
        a[4] += bA * (bfl(vvA.z) + bfl(wwA.z)) + bB * (bfl(vvB.z) + bfl(wwB.z));
        a[5] += bA * (bfh(vvA.z) + bfh(wwA.z)) + bB * (bfh(vvB.z) + bfh(wwB.z));
        a[6] += bA * (bfl(vvA.w) + bfl(wwA.w)) + bB * (bfl(vvB.w) + bfl(wwB.w));
        a[7] += bA * (bfh(vvA.w) + bfh(wwA.w)) + bB * (bfh(vvB.w) + bfh(wwB.w));
    }
    #pragma unroll
    for (int d = 0; d < 8; d++) a[d] += __shfl_xor(a[d], 8, 64);
    bs += __shfl_xor(bs, 8, 64);
    if (slot == 0) {
        float inv = 1.f / bs;
        float* hp = h + (size_t)n * 64 + li * 8;
        float o[8];
        #pragma unroll
        for (int d = 0; d < 8; d++) o[d] = hp[d] + a[d] * inv;
        *(float4*)hp = make_float4(o[0], o[1], o[2], o[3]);
        *(float4*)(hp + 4) = make_float4(o[4], o[5], o[6], o[7]);
        uint2 p8;
        p8.x = f2e5m2(o[0]) | (f2e5m2(o[1]) << 8) | (f2e5m2(o[2]) << 16) | (f2e5m2(o[3]) << 24);
        p8.y = f2e5m2(o[4]) | (f2e5m2(o[5]) << 8) | (f2e5m2(o[6]) << 16) | (f2e5m2(o[7]) << 24);
        *(uint2*)(h8 + (size_t)n * 64 + li * 8) = p8;
    }
}

// ---------------------------------------------------------------------------
// K7: relation pooling over fp8 h8. 4 lanes per 64 B row (uint4 = 16 B/lane),
// 6 gather streams (192 edges per block-iteration, 96 rows in flight per wave
// before first consume), cross-iteration pay prefetch, shuffle-based reduce.
// Lane map: li = t&3 (row quarter), side = (t>>2)&1 (src/dst), j = t>>3.
// ---------------------------------------------------------------------------
#define RP_STREAMS 6
__global__ __launch_bounds__(256) void k_relpool(const int2* __restrict__ pay,
        const int* __restrict__ start_rel, const int* __restrict__ cnt_rel,
        const unsigned char* __restrict__ h8, float* __restrict__ acc_rel) {
    int r = blockIdx.x / RSUB;
    int sub = blockIdx.x % RSUB;
    int st = start_rel[r];
    int cnt = cnt_rel[r];
    int t = threadIdx.x;
    int li = t & 3;           // 16 B quarter of the 64 B row
    int side = (t >> 2) & 1;  // 0=src, 1=dst
    int j = t >> 3;           // 0..31 edge slot within block

    int chunk = (cnt + RSUB - 1) / RSUB;
    int k0 = sub * chunk;
    int k1 = min(k0 + chunk, cnt);
    int len = k1 - k0;

    float a[16];
    #pragma unroll
    for (int d = 0; d < 16; d++) a[d] = 0.f;

    if (len > 0) {
        const int2* pp = pay + st + k0;
        int m[RP_STREAMS]; bool v[RP_STREAMS]; int2 p[RP_STREAMS];
        #pragma unroll
        for (int s = 0; s < RP_STREAMS; s++) {
            m[s] = j + s * 32;
            v[s] = m[s] < len;
            p[s] = v[s] ? pp[m[s]] : make_int2(0, 0);
        }
        for (int base = 0; base < len; base += 32 * RP_STREAMS) {
            // issue all gathers (16 scattered 64 B rows per VMEM instr)
            uint4 hv[RP_STREAMS];
            #pragma unroll
            for (int s = 0; s < RP_STREAMS; s++) {
                int idx = side ? p[s].y : p[s].x;
                hv[s] = *(const uint4*)(h8 + (size_t)idx * 64 + li * 16);
            }
            // prefetch next iteration's pay while gathers are in flight
            int mn[RP_STREAMS]; bool vn[RP_STREAMS]; int2 pn[RP_STREAMS];
            #pragma unroll
            for (int s = 0; s < RP_STREAMS; s++) {
                mn[s] = m[s] + 32 * RP_STREAMS;
                vn[s] = mn[s] < len;
                pn[s] = vn[s] ? pp[mn[s]] : make_int2(0, 0);
            }
            #pragma unroll
            for (int s = 0; s < RP_STREAMS; s++) if (v[s]) acc16(a, hv[s]);
            #pragma unroll
            for (int s = 0; s < RP_STREAMS; s++) { m[s] = mn[s]; v[s] = vn[s]; p[s] = pn[s]; }
        }
    }

    // wave reduce over the 8 j-slots in this wave (lane bits 3,4,5)
    #pragma unroll
    for (int d = 0; d < 16; d++) {
        a[d] += __shfl_xor(a[d], 8, 64);
        a[d] += __shfl_xor(a[d], 16, 64);
        a[d] += __shfl_xor(a[d], 32, 64);
    }

    // cross-wave reduce via tiny LDS (2 KB), then 128 atomics per block
    __shared__ float red[4][8][16];
    int wv = t >> 6;
    int lane = t & 63;
    if (lane < 8) {
        #pragma unroll
        for (int d = 0; d < 16; d++) red[wv][lane][d] = a[d];
    }
    __syncthreads();
    if (t < 128) {
        int sl = t >> 4;   // (side<<2)|li
        int d = t & 15;
        float s = red[0][sl][d] + red[1][sl][d] + red[2][sl][d] + red[3][sl][d];
        int sd = sl >> 2;
        int li2 = sl & 3;
        atomicAdd(&acc_rel[r * 128 + sd * 64 + li2 * 16 + d], s);
    }
}

// K8: mean + h_rel = mean @ W_rel3.T + b_rel3
__global__ void k_relfin(const float* __restrict__ acc_rel, const int* __restrict__ cnt_rel,
                         const float* __restrict__ Qr, const float* __restrict__ W_rel3,
                         const float* __restrict__ b_rel3, float* __restrict__ out) {
    int g = blockIdx.x * 256 + threadIdx.x;
    if (g >= N_RELS * 64) return;
    int r = g >> 6;
    int j = g & 63;
    int cnt = cnt_rel[r];
    float invc = 1.f / (float)(cnt > 0 ? cnt : 1);
    float s = b_rel3[j];
    for (int k = 0; k < 128; k++) s += acc_rel[r * 128 + k] * invc * W_rel3[j * 192 + k];
    if (cnt > 0)
        for (int k = 0; k < 64; k++) s += Qr[r * 64 + k] * W_rel3[j * 192 + 128 + k];
    out[g] = s;
}

extern "C" void kernel_launch(void* const* d_in, const int* in_sizes, int n_in,
                              void* d_out, int out_size, void* d_ws, size_t ws_size,
                              hipStream_t stream) {
    const float* ent    = (const float*)d_in[0];
    const float* relE   = (const float*)d_in[1];
    const float* W_ent  = (const float*)d_in[2];
    const float* b_ent  = (const float*)d_in[3];
    const float* W_relL = (const float*)d_in[4];
    const float* b_relL = (const float*)d_in[5];
    const float* W_rel2 = (const float*)d_in[6];
    const float* b_rel2 = (const float*)d_in[7];
    const float* W_rel3 = (const float*)d_in[8];
    const float* b_rel3 = (const float*)d_in[9];
    const float* W_a    = (const float*)d_in[10];
    const float* b_a    = (const float*)d_in[11];
    const float* W_fc   = (const float*)d_in[12];
    const float* b_fc   = (const float*)d_in[13];
    const int* src = (const int*)d_in[14];
    const int* dst = (const int*)d_in[15];
    const int* rel = (const int*)d_in[16];
    float* out = (float*)d_out;

    char* ws = (char*)d_ws;
    size_t off = 0;
    auto alloc = [&](size_t bytes) -> void* {
        void* p = ws + off;
        off += (bytes + 255) & ~(size_t)255;
        return p;
    };
    float* Wcat = (float*)alloc(8192 * 4);
    float* dcat = (float*)alloc(128 * 4);
    float* MW  = (float*)alloc(4096 * 4);
    float* MQ  = (float*)alloc(4096 * 4);
    float* dW  = (float*)alloc(64 * 4);
    float* dQ  = (float*)alloc(64 * 4);
    unsigned short* V16 = (unsigned short*)alloc((size_t)N_NODES * 64 * 2);
    unsigned char* h8 = (unsigned char*)alloc((size_t)N_NODES * 64);
    float* us  = (float*)alloc((size_t)N_NODES * 4);
    float* vs  = (float*)alloc((size_t)N_NODES * 4);
    unsigned short* Wr16 = (unsigned short*)alloc((size_t)N_RELS * 64 * 2);
    float* Qr  = (float*)alloc((size_t)N_RELS * 64 * 4);
    float* wsr = (float*)alloc((size_t)N_RELS * 4);
    int* cnt_src   = (int*)alloc((size_t)N_NODES * 4);
    int* start_src = (int*)alloc((size_t)N_NODES * 4);
    int* cnts      = (int*)alloc((size_t)NROWS * 4);   // [0..499]=cnt_rel, [500..]=bucket_cnt
    int* starts    = (int*)alloc((size_t)NROWS * 4);
    int* blkhist   = (int*)alloc((size_t)NROWS * NB_E * 4);
    int* blkbase   = (int*)alloc((size_t)NROWS * NB_E * 4);
    int* stg_a     = (int*)alloc((size_t)N_EDGES * 4);
    int* stg_b     = (int*)alloc((size_t)N_EDGES * 4);
    int2* pay_src  = (int2*)alloc((size_t)N_EDGES * 8);
    float* pay_b   = (float*)alloc((size_t)N_EDGES * 4);
    int2* pay_rel  = (int2*)alloc((size_t)N_EDGES * 8);
    float* acc_rel = (float*)alloc((size_t)N_RELS * 128 * 4);

    int* cnt_rel    = cnts;
    int* bucket_cnt = cnts + N_RELS;

    k_zero<<<(NROWS + 255) / 256, 256, 0, stream>>>(cnts, NROWS);
    k_zero<<<(N_RELS * 128 + 255) / 256, 256, 0, stream>>>((int*)acc_rel, N_RELS * 128);

    k_fold<<<65, 256, 0, stream>>>(W_ent, b_ent, W_relL, b_relL, W_rel2, b_rel2,
                                   W_fc, b_fc, Wcat, dcat, MW, MQ, dW, dQ);
    k_node<<<(N_NODES + 63) / 64, 256, 0, stream>>>(ent, Wcat, dcat, W_a, out, V16, us, vs);
    k_relproj<<<125, 256, 0, stream>>>(relE, MW, MQ, dW, dQ, W_a, Wr16, Qr, wsr);
    k_hist<<<NB_E, 256, 0, stream>>>(src, rel, cnt_rel, bucket_cnt, blkhist);
    k_scan_two<<<2, 256, 0, stream>>>(cnt_rel, bucket_cnt, starts);
    k_scan_relblk<<<(NROWS * 64 + 255) / 256, 256, 0, stream>>>(starts, blkhist, blkbase);
    k_scatter<<<NB_E, 256, 0, stream>>>(src, dst, rel, blkbase, pay_rel, stg_a, stg_b);
    k_sortb<<<NBKT, 1024, 0, stream>>>(stg_a, stg_b, starts, bucket_cnt,
                                       us, vs, wsr, b_a,
                                       pay_src, pay_b, start_src, cnt_src);
    k_attn<<<(N_NODES + 15) / 16, 256, 0, stream>>>(pay_src, pay_b, start_src, cnt_src,
                                                    V16, Wr16, out, h8);
    k_relpool<<<N_RELS * RSUB, 256, 0, stream>>>(pay_rel, starts, cnt_rel, h8, acc_rel);
    k_relfin<<<(N_RELS * 64 + 255) / 256, 256, 0, stream>>>(acc_rel, cnt_rel, Qr, W_rel3,
                                                            b_rel3, out + (size_t)N_NODES * 64);
}